// Round 1
// baseline (1534.164 us; speedup 1.0000x reference)
//
#include <hip/hip_runtime.h>
#include <stdint.h>

#define NN 100000
#define NE 1600000
#define DIM 128
#define BN_EPS 1e-5f

// ---------------- setup: degree histogram, dinv, CSR build ----------------

__global__ __launch_bounds__(256) void k_hist(const int* __restrict__ ei,
                                              int* __restrict__ deg_row,
                                              int* __restrict__ cnt_col) {
    int e = blockIdx.x * 256 + threadIdx.x;
    if (e < NE) {
        atomicAdd(&deg_row[ei[e]], 1);
        atomicAdd(&cnt_col[ei[NE + e]], 1);
    }
}

__global__ __launch_bounds__(256) void k_dinv(const int* __restrict__ deg_row,
                                              float* __restrict__ dinv) {
    int v = blockIdx.x * 256 + threadIdx.x;
    if (v < NN) dinv[v] = rsqrtf((float)deg_row[v] + 1.0f);
}

// exclusive scan of cnt_col -> offs, 2-level (391 blocks of 256)
__global__ __launch_bounds__(256) void k_scan1(const int* __restrict__ cnt,
                                               int* __restrict__ offs,
                                               int* __restrict__ bsum) {
    __shared__ int s[256];
    int t = threadIdx.x;
    int i = blockIdx.x * 256 + t;
    int v = (i < NN) ? cnt[i] : 0;
    s[t] = v;
    __syncthreads();
    for (int d = 1; d < 256; d <<= 1) {
        int add = (t >= d) ? s[t - d] : 0;
        __syncthreads();
        s[t] += add;
        __syncthreads();
    }
    if (i < NN) offs[i] = s[t] - v;          // exclusive within block
    if (t == 255) bsum[blockIdx.x] = s[t];   // block total
}

__global__ __launch_bounds__(512) void k_scan2(const int* __restrict__ bsum,
                                               int* __restrict__ bofs, int nb) {
    __shared__ int s[512];
    int t = threadIdx.x;
    int v = (t < nb) ? bsum[t] : 0;
    s[t] = v;
    __syncthreads();
    for (int d = 1; d < 512; d <<= 1) {
        int add = (t >= d) ? s[t - d] : 0;
        __syncthreads();
        s[t] += add;
        __syncthreads();
    }
    if (t < nb) bofs[t] = s[t] - v;          // exclusive
}

__global__ __launch_bounds__(256) void k_scan3(int* __restrict__ offs,
                                               const int* __restrict__ bofs,
                                               int* __restrict__ cursor) {
    int i = blockIdx.x * 256 + threadIdx.x;
    if (i < NN) {
        int o = offs[i] + bofs[blockIdx.x];
        offs[i] = o;
        cursor[i] = o;
    }
    if (i == 0) offs[NN] = NE;
}

// place each edge into CSR-by-destination; inline norm + edge_attr
__global__ __launch_bounds__(256) void k_fill(const int* __restrict__ ei,
                                              const float* __restrict__ ea,
                                              const float* __restrict__ dinv,
                                              int* __restrict__ cursor,
                                              int* __restrict__ csr_row,
                                              float4* __restrict__ csr_meta) {
    int e = blockIdx.x * 256 + threadIdx.x;
    if (e < NE) {
        int r = ei[e];
        int c = ei[NE + e];
        int p = atomicAdd(&cursor[c], 1);
        csr_row[p] = r;
        csr_meta[p] = make_float4(dinv[r] * dinv[c], ea[e * 3], ea[e * 3 + 1], ea[e * 3 + 2]);
    }
}

// ---------------- BN folding helpers ----------------

__global__ void k_initAB(float* __restrict__ A, float* __restrict__ B) {
    int j = threadIdx.x;
    A[j] = 1.0f;
    B[j] = 0.0f;
}

// W_eff[k][j] = A[k] * W[k][j]
__global__ __launch_bounds__(128) void k_prep_w(const float* __restrict__ W,
                                                const float* __restrict__ A,
                                                float* __restrict__ Weff) {
    int k = blockIdx.x, j = threadIdx.x;
    Weff[k * DIM + j] = A[k] * W[k * DIM + j];
}

// b_eff[j] = b[j] + sum_k B[k]*W[k][j]; also zero the BN stats accumulators
__global__ __launch_bounds__(128) void k_prep_b(const float* __restrict__ W,
                                                const float* __restrict__ b,
                                                const float* __restrict__ Bv,
                                                float* __restrict__ beff,
                                                float* __restrict__ stats) {
    int j = blockIdx.x, k = threadIdx.x;
    __shared__ float s[128];
    s[k] = Bv[k] * W[k * DIM + j];
    __syncthreads();
    for (int d = 64; d > 0; d >>= 1) {
        if (k < d) s[k] += s[k + d];
        __syncthreads();
    }
    if (k == 0) {
        beff[j] = b[j] + s[0];
        stats[j] = 0.0f;
        stats[DIM + j] = 0.0f;
    }
}

// ---------------- GEMM: Y[M,128] = X[M,128] @ W[128,128] + b ----------------
// block = 256 threads, 32 rows/block; thread computes 4 rows x 4 cols

__device__ __forceinline__ void fma4(float4& a, float s, const float4& w) {
    a.x = fmaf(s, w.x, a.x);
    a.y = fmaf(s, w.y, a.y);
    a.z = fmaf(s, w.z, a.z);
    a.w = fmaf(s, w.w, a.w);
}

__global__ __launch_bounds__(256) void k_gemm(const float* __restrict__ X,
                                              const float* __restrict__ W,
                                              const float* __restrict__ b,
                                              float* __restrict__ Y) {
    int tid = threadIdx.x;
    int c4 = (tid & 31) * 4;        // col group
    int rg = tid >> 5;              // 0..7
    int r0 = blockIdx.x * 32 + rg * 4;

    float4 acc0 = {0, 0, 0, 0}, acc1 = {0, 0, 0, 0}, acc2 = {0, 0, 0, 0}, acc3 = {0, 0, 0, 0};
    const float* x0 = X + (size_t)r0 * DIM;

    for (int k = 0; k < DIM; k += 4) {
        float4 w0 = *(const float4*)&W[(k + 0) * DIM + c4];
        float4 w1 = *(const float4*)&W[(k + 1) * DIM + c4];
        float4 w2 = *(const float4*)&W[(k + 2) * DIM + c4];
        float4 w3 = *(const float4*)&W[(k + 3) * DIM + c4];
        float4 xa = *(const float4*)&x0[0 * DIM + k];
        float4 xb = *(const float4*)&x0[1 * DIM + k];
        float4 xc = *(const float4*)&x0[2 * DIM + k];
        float4 xd = *(const float4*)&x0[3 * DIM + k];
        fma4(acc0, xa.x, w0); fma4(acc0, xa.y, w1); fma4(acc0, xa.z, w2); fma4(acc0, xa.w, w3);
        fma4(acc1, xb.x, w0); fma4(acc1, xb.y, w1); fma4(acc1, xb.z, w2); fma4(acc1, xb.w, w3);
        fma4(acc2, xc.x, w0); fma4(acc2, xc.y, w1); fma4(acc2, xc.z, w2); fma4(acc2, xc.w, w3);
        fma4(acc3, xd.x, w0); fma4(acc3, xd.y, w1); fma4(acc3, xd.z, w2); fma4(acc3, xd.w, w3);
    }

    float4 bb = *(const float4*)&b[c4];
    acc0.x += bb.x; acc0.y += bb.y; acc0.z += bb.z; acc0.w += bb.w;
    acc1.x += bb.x; acc1.y += bb.y; acc1.z += bb.z; acc1.w += bb.w;
    acc2.x += bb.x; acc2.y += bb.y; acc2.z += bb.z; acc2.w += bb.w;
    acc3.x += bb.x; acc3.y += bb.y; acc3.z += bb.z; acc3.w += bb.w;

    *(float4*)&Y[(size_t)(r0 + 0) * DIM + c4] = acc0;
    *(float4*)&Y[(size_t)(r0 + 1) * DIM + c4] = acc1;
    *(float4*)&Y[(size_t)(r0 + 2) * DIM + c4] = acc2;
    *(float4*)&Y[(size_t)(r0 + 3) * DIM + c4] = acc3;
}

// ---------------- aggregation: one wave per destination node ----------------
// t[v] = relu( sum_{edges into v} norm * relu(h[row] + edge_attr@We + be) )

__global__ __launch_bounds__(256) void k_agg(const float* __restrict__ h,
                                             const int* __restrict__ csr_row,
                                             const float4* __restrict__ csr_meta,
                                             const int* __restrict__ offs,
                                             const float* __restrict__ We,
                                             const float* __restrict__ be,
                                             float* __restrict__ t) {
    int wave = threadIdx.x >> 6;
    int lane = threadIdx.x & 63;
    int v = blockIdx.x * 4 + wave;
    if (v >= NN) return;
    int j = lane * 2;

    float w0a = We[j],           w0b = We[j + 1];
    float w1a = We[DIM + j],     w1b = We[DIM + j + 1];
    float w2a = We[2 * DIM + j], w2b = We[2 * DIM + j + 1];
    float b0 = be[j], b1 = be[j + 1];

    float acc0 = 0.0f, acc1 = 0.0f;
    int s = offs[v], e = offs[v + 1];
    for (int i = s; i < e; ++i) {
        int r = csr_row[i];
        float4 m = csr_meta[i];
        float2 hv = *(const float2*)&h[(size_t)r * DIM + j];
        float e0 = fmaf(m.y, w0a, fmaf(m.z, w1a, fmaf(m.w, w2a, b0)));
        float e1 = fmaf(m.y, w0b, fmaf(m.z, w1b, fmaf(m.w, w2b, b1)));
        float p0 = fmaxf(hv.x + e0, 0.0f);
        float p1 = fmaxf(hv.y + e1, 0.0f);
        acc0 = fmaf(m.x, p0, acc0);
        acc1 = fmaf(m.x, p1, acc1);
    }
    float2 o;
    o.x = fmaxf(acc0, 0.0f);   // outer relu before BN
    o.y = fmaxf(acc1, 0.0f);
    *(float2*)&t[(size_t)v * DIM + j] = o;
}

// ---------------- BN statistics over t ----------------

__global__ __launch_bounds__(256) void k_stats(const float* __restrict__ t,
                                               float* __restrict__ stats) {
    int j = threadIdx.x & 127;
    int half = threadIdx.x >> 7;  // 0 or 1
    float s = 0.0f, q = 0.0f;
    for (int r = blockIdx.x * 2 + half; r < NN; r += 512) {
        float v = t[(size_t)r * DIM + j];
        s += v;
        q = fmaf(v, v, q);
    }
    __shared__ float ls[256], lq[256];
    ls[threadIdx.x] = s;
    lq[threadIdx.x] = q;
    __syncthreads();
    if (half == 0) {
        s += ls[threadIdx.x + 128];
        q += lq[threadIdx.x + 128];
        atomicAdd(&stats[j], s);
        atomicAdd(&stats[DIM + j], q);
    }
}

__global__ void k_coeff(const float* __restrict__ stats,
                        const float* __restrict__ g,
                        const float* __restrict__ bt,
                        float* __restrict__ A, float* __restrict__ B) {
    int j = threadIdx.x;
    float m = stats[j] * (1.0f / NN);
    float var = stats[DIM + j] * (1.0f / NN) - m * m;
    float rs = rsqrtf(var + BN_EPS);
    float a = rs * g[j];
    A[j] = a;
    B[j] = bt[j] - m * a;
}

// ---------------- launch ----------------

static inline char* alignp(char* p, size_t a) {
    return (char*)(((uintptr_t)p + a - 1) & ~(uintptr_t)(a - 1));
}

extern "C" void kernel_launch(void* const* d_in, const int* in_sizes, int n_in,
                              void* d_out, int out_size, void* d_ws, size_t ws_size,
                              hipStream_t stream) {
    const float* x   = (const float*)d_in[0];
    const int*   ei  = (const int*)d_in[1];
    const float* ea  = (const float*)d_in[2];
    const float* Wp[3]  = {(const float*)d_in[3],  (const float*)d_in[9],  (const float*)d_in[15]};
    const float* bp[3]  = {(const float*)d_in[4],  (const float*)d_in[10], (const float*)d_in[16]};
    const float* Wep[3] = {(const float*)d_in[5],  (const float*)d_in[11], (const float*)d_in[17]};
    const float* bep[3] = {(const float*)d_in[6],  (const float*)d_in[12], (const float*)d_in[18]};
    const float* gp[3]  = {(const float*)d_in[7],  (const float*)d_in[13], (const float*)d_in[19]};
    const float* btp[3] = {(const float*)d_in[8],  (const float*)d_in[14], (const float*)d_in[20]};
    const float* Wl  = (const float*)d_in[21];
    const float* bl  = (const float*)d_in[22];
    float* out = (float*)d_out;

    char* p = (char*)d_ws;
    auto alloc = [&](size_t bytes) -> void* {
        p = alignp(p, 256);
        void* r = (void*)p;
        p += bytes;
        return r;
    };

    int*    deg_row  = (int*)alloc(NN * sizeof(int));
    int*    cnt_col  = (int*)alloc(NN * sizeof(int));
    int*    cursor   = (int*)alloc(NN * sizeof(int));
    int*    offs     = (int*)alloc((NN + 1) * sizeof(int));
    int*    bsum     = (int*)alloc(512 * sizeof(int));
    int*    bofs     = (int*)alloc(512 * sizeof(int));
    float*  dinv     = (float*)alloc(NN * sizeof(float));
    int*    csr_row  = (int*)alloc((size_t)NE * sizeof(int));
    float4* csr_meta = (float4*)alloc((size_t)NE * sizeof(float4));
    float*  h        = (float*)alloc((size_t)NN * DIM * sizeof(float));
    float*  t        = (float*)alloc((size_t)NN * DIM * sizeof(float));
    float*  Weff     = (float*)alloc(DIM * DIM * sizeof(float));
    float*  beff     = (float*)alloc(DIM * sizeof(float));
    float*  Av       = (float*)alloc(DIM * sizeof(float));
    float*  Bv       = (float*)alloc(DIM * sizeof(float));
    float*  stats    = (float*)alloc(2 * DIM * sizeof(float));

    const int NB_E = (NE + 255) / 256;   // 6250
    const int NB_N = (NN + 255) / 256;   // 391

    // --- setup: CSR by destination (reused across all 3 layers) ---
    hipMemsetAsync(deg_row, 0, NN * sizeof(int), stream);
    hipMemsetAsync(cnt_col, 0, NN * sizeof(int), stream);
    k_hist<<<NB_E, 256, 0, stream>>>(ei, deg_row, cnt_col);
    k_dinv<<<NB_N, 256, 0, stream>>>(deg_row, dinv);
    k_scan1<<<NB_N, 256, 0, stream>>>(cnt_col, offs, bsum);
    k_scan2<<<1, 512, 0, stream>>>(bsum, bofs, NB_N);
    k_scan3<<<NB_N, 256, 0, stream>>>(offs, bofs, cursor);
    k_fill<<<NB_E, 256, 0, stream>>>(ei, ea, dinv, cursor, csr_row, csr_meta);

    k_initAB<<<1, 128, 0, stream>>>(Av, Bv);

    const float* Xin = x;
    for (int l = 0; l < 3; ++l) {
        k_prep_w<<<128, 128, 0, stream>>>(Wp[l], Av, Weff);
        k_prep_b<<<128, 128, 0, stream>>>(Wp[l], bp[l], Bv, beff, stats);
        k_gemm<<<NN / 32, 256, 0, stream>>>(Xin, Weff, beff, h);
        k_agg<<<NN / 4, 256, 0, stream>>>(h, csr_row, csr_meta, offs, Wep[l], bep[l], t);
        k_stats<<<256, 256, 0, stream>>>(t, stats);
        k_coeff<<<1, 128, 0, stream>>>(stats, gp[l], btp[l], Av, Bv);
        Xin = t;
    }

    // final linear with BN3 folded in
    k_prep_w<<<128, 128, 0, stream>>>(Wl, Av, Weff);
    k_prep_b<<<128, 128, 0, stream>>>(Wl, bl, Bv, beff, stats);
    k_gemm<<<NN / 32, 256, 0, stream>>>(t, Weff, beff, out);
}

// Round 2
// 1272.085 us; speedup vs baseline: 1.2060x; 1.2060x over previous
//
#include <hip/hip_runtime.h>
#include <stdint.h>

#define NN 100000
#define NE 1600000
#define DIM 128
#define BN_EPS 1e-5f

typedef unsigned int uint;
typedef unsigned short ushort;

// ---------------- bf16 helpers ----------------

static __device__ __forceinline__ ushort f2bf(float f) {
    uint u = __float_as_uint(f);
    u += 0x7FFF + ((u >> 16) & 1);   // round-to-nearest-even
    return (ushort)(u >> 16);
}
static __device__ __forceinline__ float bf_lo(uint p) {
    return __uint_as_float(p << 16);
}
static __device__ __forceinline__ float bf_hi(uint p) {
    return __uint_as_float(p & 0xFFFF0000u);
}

// ---------------- setup: degree histogram, dinv, CSR build ----------------

__global__ __launch_bounds__(256) void k_hist(const int* __restrict__ ei,
                                              int* __restrict__ deg_row,
                                              int* __restrict__ cnt_col) {
    int e = blockIdx.x * 256 + threadIdx.x;
    if (e < NE) {
        atomicAdd(&deg_row[ei[e]], 1);
        atomicAdd(&cnt_col[ei[NE + e]], 1);
    }
}

__global__ __launch_bounds__(256) void k_dinv(const int* __restrict__ deg_row,
                                              float* __restrict__ dinv) {
    int v = blockIdx.x * 256 + threadIdx.x;
    if (v < NN) dinv[v] = rsqrtf((float)deg_row[v] + 1.0f);
}

__global__ __launch_bounds__(256) void k_scan1(const int* __restrict__ cnt,
                                               int* __restrict__ offs,
                                               int* __restrict__ bsum) {
    __shared__ int s[256];
    int t = threadIdx.x;
    int i = blockIdx.x * 256 + t;
    int v = (i < NN) ? cnt[i] : 0;
    s[t] = v;
    __syncthreads();
    for (int d = 1; d < 256; d <<= 1) {
        int add = (t >= d) ? s[t - d] : 0;
        __syncthreads();
        s[t] += add;
        __syncthreads();
    }
    if (i < NN) offs[i] = s[t] - v;
    if (t == 255) bsum[blockIdx.x] = s[t];
}

__global__ __launch_bounds__(512) void k_scan2(const int* __restrict__ bsum,
                                               int* __restrict__ bofs, int nb) {
    __shared__ int s[512];
    int t = threadIdx.x;
    int v = (t < nb) ? bsum[t] : 0;
    s[t] = v;
    __syncthreads();
    for (int d = 1; d < 512; d <<= 1) {
        int add = (t >= d) ? s[t - d] : 0;
        __syncthreads();
        s[t] += add;
        __syncthreads();
    }
    if (t < nb) bofs[t] = s[t] - v;
}

__global__ __launch_bounds__(256) void k_scan3(int* __restrict__ offs,
                                               const int* __restrict__ bofs,
                                               int* __restrict__ cursor) {
    int i = blockIdx.x * 256 + threadIdx.x;
    if (i < NN) {
        int o = offs[i] + bofs[blockIdx.x];
        offs[i] = o;
        cursor[i] = o;
    }
    if (i == 0) offs[NN] = NE;
}

__global__ __launch_bounds__(256) void k_fill(const int* __restrict__ ei,
                                              const float* __restrict__ ea,
                                              const float* __restrict__ dinv,
                                              int* __restrict__ cursor,
                                              int* __restrict__ csr_row,
                                              float4* __restrict__ csr_meta) {
    int e = blockIdx.x * 256 + threadIdx.x;
    if (e < NE) {
        int r = ei[e];
        int c = ei[NE + e];
        int p = atomicAdd(&cursor[c], 1);
        csr_row[p] = r;
        csr_meta[p] = make_float4(dinv[r] * dinv[c], ea[e * 3], ea[e * 3 + 1], ea[e * 3 + 2]);
    }
}

// ---------------- BN folding helpers ----------------

__global__ void k_initAB(float* __restrict__ A, float* __restrict__ B) {
    int j = threadIdx.x;
    A[j] = 1.0f;
    B[j] = 0.0f;
}

__global__ __launch_bounds__(128) void k_prep_w(const float* __restrict__ W,
                                                const float* __restrict__ A,
                                                float* __restrict__ Weff) {
    int k = blockIdx.x, j = threadIdx.x;
    Weff[k * DIM + j] = A[k] * W[k * DIM + j];
}

__global__ __launch_bounds__(128) void k_prep_b(const float* __restrict__ W,
                                                const float* __restrict__ b,
                                                const float* __restrict__ Bv,
                                                float* __restrict__ beff,
                                                float* __restrict__ stats) {
    int j = blockIdx.x, k = threadIdx.x;
    __shared__ float s[128];
    s[k] = Bv[k] * W[k * DIM + j];
    __syncthreads();
    for (int d = 64; d > 0; d >>= 1) {
        if (k < d) s[k] += s[k + d];
        __syncthreads();
    }
    if (k == 0) {
        beff[j] = b[j] + s[0];
        stats[j] = 0.0f;
        stats[DIM + j] = 0.0f;
    }
}

// ---------------- GEMM: Y[M,128] = X[M,128] @ W[128,128] + b ----------------

__device__ __forceinline__ void fma4(float4& a, float s, const float4& w) {
    a.x = fmaf(s, w.x, a.x);
    a.y = fmaf(s, w.y, a.y);
    a.z = fmaf(s, w.z, a.z);
    a.w = fmaf(s, w.w, a.w);
}

// core: computes 4 rows x 4 cols per thread into acc[4]
#define GEMM_BODY                                                                 \
    int tid = threadIdx.x;                                                        \
    int c4 = (tid & 31) * 4;                                                      \
    int rg = tid >> 5;                                                            \
    int r0 = blockIdx.x * 32 + rg * 4;                                            \
    float4 acc0 = {0, 0, 0, 0}, acc1 = {0, 0, 0, 0};                              \
    float4 acc2 = {0, 0, 0, 0}, acc3 = {0, 0, 0, 0};                              \
    const float* x0 = X + (size_t)r0 * DIM;                                       \
    for (int k = 0; k < DIM; k += 4) {                                            \
        float4 w0 = *(const float4*)&W[(k + 0) * DIM + c4];                       \
        float4 w1 = *(const float4*)&W[(k + 1) * DIM + c4];                       \
        float4 w2 = *(const float4*)&W[(k + 2) * DIM + c4];                       \
        float4 w3 = *(const float4*)&W[(k + 3) * DIM + c4];                       \
        float4 xa = *(const float4*)&x0[0 * DIM + k];                             \
        float4 xb = *(const float4*)&x0[1 * DIM + k];                             \
        float4 xc = *(const float4*)&x0[2 * DIM + k];                             \
        float4 xd = *(const float4*)&x0[3 * DIM + k];                             \
        fma4(acc0, xa.x, w0); fma4(acc0, xa.y, w1); fma4(acc0, xa.z, w2); fma4(acc0, xa.w, w3); \
        fma4(acc1, xb.x, w0); fma4(acc1, xb.y, w1); fma4(acc1, xb.z, w2); fma4(acc1, xb.w, w3); \
        fma4(acc2, xc.x, w0); fma4(acc2, xc.y, w1); fma4(acc2, xc.z, w2); fma4(acc2, xc.w, w3); \
        fma4(acc3, xd.x, w0); fma4(acc3, xd.y, w1); fma4(acc3, xd.z, w2); fma4(acc3, xd.w, w3); \
    }                                                                             \
    float4 bb = *(const float4*)&b[c4];                                           \
    acc0.x += bb.x; acc0.y += bb.y; acc0.z += bb.z; acc0.w += bb.w;               \
    acc1.x += bb.x; acc1.y += bb.y; acc1.z += bb.z; acc1.w += bb.w;               \
    acc2.x += bb.x; acc2.y += bb.y; acc2.z += bb.z; acc2.w += bb.w;               \
    acc3.x += bb.x; acc3.y += bb.y; acc3.z += bb.z; acc3.w += bb.w;

// fp32 output (final linear)
__global__ __launch_bounds__(256) void k_gemm(const float* __restrict__ X,
                                              const float* __restrict__ W,
                                              const float* __restrict__ b,
                                              float* __restrict__ Y) {
    GEMM_BODY
    *(float4*)&Y[(size_t)(r0 + 0) * DIM + c4] = acc0;
    *(float4*)&Y[(size_t)(r0 + 1) * DIM + c4] = acc1;
    *(float4*)&Y[(size_t)(r0 + 2) * DIM + c4] = acc2;
    *(float4*)&Y[(size_t)(r0 + 3) * DIM + c4] = acc3;
}

// bf16 output (h for the gather)
__global__ __launch_bounds__(256) void k_gemm_bf(const float* __restrict__ X,
                                                 const float* __restrict__ W,
                                                 const float* __restrict__ b,
                                                 ushort* __restrict__ Y) {
    GEMM_BODY
    ushort4 p0 = {f2bf(acc0.x), f2bf(acc0.y), f2bf(acc0.z), f2bf(acc0.w)};
    ushort4 p1 = {f2bf(acc1.x), f2bf(acc1.y), f2bf(acc1.z), f2bf(acc1.w)};
    ushort4 p2 = {f2bf(acc2.x), f2bf(acc2.y), f2bf(acc2.z), f2bf(acc2.w)};
    ushort4 p3 = {f2bf(acc3.x), f2bf(acc3.y), f2bf(acc3.z), f2bf(acc3.w)};
    *(ushort4*)&Y[(size_t)(r0 + 0) * DIM + c4] = p0;
    *(ushort4*)&Y[(size_t)(r0 + 1) * DIM + c4] = p1;
    *(ushort4*)&Y[(size_t)(r0 + 2) * DIM + c4] = p2;
    *(ushort4*)&Y[(size_t)(r0 + 3) * DIM + c4] = p3;
}

// ---------------- aggregation: one wave per destination node ----------------
// t[v] = relu( sum_{edges into v} norm * relu(h_bf16[row] + edge_attr@We + be) )
// unroll x4: 4 independent gathers in flight per wave

__global__ __launch_bounds__(256) void k_agg(const uint* __restrict__ hb,
                                             const int* __restrict__ csr_row,
                                             const float4* __restrict__ csr_meta,
                                             const int* __restrict__ offs,
                                             const float* __restrict__ We,
                                             const float* __restrict__ be,
                                             float* __restrict__ t) {
    int wave = threadIdx.x >> 6;
    int lane = threadIdx.x & 63;
    int v = blockIdx.x * 4 + wave;
    if (v >= NN) return;
    int j = lane * 2;

    float w0a = We[j],           w0b = We[j + 1];
    float w1a = We[DIM + j],     w1b = We[DIM + j + 1];
    float w2a = We[2 * DIM + j], w2b = We[2 * DIM + j + 1];
    float b0 = be[j], b1 = be[j + 1];

    float a0 = 0.0f, a1 = 0.0f;   // acc pair A (edges 0,2 of group)
    float c0 = 0.0f, c1 = 0.0f;   // acc pair B (edges 1,3 of group)
    int s = offs[v], e = offs[v + 1];
    int i = s;
    for (; i + 4 <= e; i += 4) {
        int r0 = csr_row[i], r1 = csr_row[i + 1], r2 = csr_row[i + 2], r3 = csr_row[i + 3];
        float4 m0 = csr_meta[i], m1 = csr_meta[i + 1], m2 = csr_meta[i + 2], m3 = csr_meta[i + 3];
        uint hv0 = hb[(size_t)r0 * 64 + lane];
        uint hv1 = hb[(size_t)r1 * 64 + lane];
        uint hv2 = hb[(size_t)r2 * 64 + lane];
        uint hv3 = hb[(size_t)r3 * 64 + lane];
        float e00 = fmaf(m0.y, w0a, fmaf(m0.z, w1a, fmaf(m0.w, w2a, b0)));
        float e01 = fmaf(m0.y, w0b, fmaf(m0.z, w1b, fmaf(m0.w, w2b, b1)));
        float e10 = fmaf(m1.y, w0a, fmaf(m1.z, w1a, fmaf(m1.w, w2a, b0)));
        float e11 = fmaf(m1.y, w0b, fmaf(m1.z, w1b, fmaf(m1.w, w2b, b1)));
        float e20 = fmaf(m2.y, w0a, fmaf(m2.z, w1a, fmaf(m2.w, w2a, b0)));
        float e21 = fmaf(m2.y, w0b, fmaf(m2.z, w1b, fmaf(m2.w, w2b, b1)));
        float e30 = fmaf(m3.y, w0a, fmaf(m3.z, w1a, fmaf(m3.w, w2a, b0)));
        float e31 = fmaf(m3.y, w0b, fmaf(m3.z, w1b, fmaf(m3.w, w2b, b1)));
        a0 = fmaf(m0.x, fmaxf(bf_lo(hv0) + e00, 0.0f), a0);
        a1 = fmaf(m0.x, fmaxf(bf_hi(hv0) + e01, 0.0f), a1);
        c0 = fmaf(m1.x, fmaxf(bf_lo(hv1) + e10, 0.0f), c0);
        c1 = fmaf(m1.x, fmaxf(bf_hi(hv1) + e11, 0.0f), c1);
        a0 = fmaf(m2.x, fmaxf(bf_lo(hv2) + e20, 0.0f), a0);
        a1 = fmaf(m2.x, fmaxf(bf_hi(hv2) + e21, 0.0f), a1);
        c0 = fmaf(m3.x, fmaxf(bf_lo(hv3) + e30, 0.0f), c0);
        c1 = fmaf(m3.x, fmaxf(bf_hi(hv3) + e31, 0.0f), c1);
    }
    for (; i < e; ++i) {
        int r = csr_row[i];
        float4 m = csr_meta[i];
        uint hv = hb[(size_t)r * 64 + lane];
        float e0 = fmaf(m.y, w0a, fmaf(m.z, w1a, fmaf(m.w, w2a, b0)));
        float e1 = fmaf(m.y, w0b, fmaf(m.z, w1b, fmaf(m.w, w2b, b1)));
        a0 = fmaf(m.x, fmaxf(bf_lo(hv) + e0, 0.0f), a0);
        a1 = fmaf(m.x, fmaxf(bf_hi(hv) + e1, 0.0f), a1);
    }
    float2 o;
    o.x = fmaxf(a0 + c0, 0.0f);
    o.y = fmaxf(a1 + c1, 0.0f);
    *(float2*)&t[(size_t)v * DIM + j] = o;
}

// ---------------- BN statistics over t ----------------

__global__ __launch_bounds__(256) void k_stats(const float* __restrict__ t,
                                               float* __restrict__ stats) {
    int j = threadIdx.x & 127;
    int half = threadIdx.x >> 7;
    float s = 0.0f, q = 0.0f;
    for (int r = blockIdx.x * 2 + half; r < NN; r += 512) {
        float v = t[(size_t)r * DIM + j];
        s += v;
        q = fmaf(v, v, q);
    }
    __shared__ float ls[256], lq[256];
    ls[threadIdx.x] = s;
    lq[threadIdx.x] = q;
    __syncthreads();
    if (half == 0) {
        s += ls[threadIdx.x + 128];
        q += lq[threadIdx.x + 128];
        atomicAdd(&stats[j], s);
        atomicAdd(&stats[DIM + j], q);
    }
}

__global__ void k_coeff(const float* __restrict__ stats,
                        const float* __restrict__ g,
                        const float* __restrict__ bt,
                        float* __restrict__ A, float* __restrict__ B) {
    int j = threadIdx.x;
    float m = stats[j] * (1.0f / NN);
    float var = stats[DIM + j] * (1.0f / NN) - m * m;
    float rs = rsqrtf(var + BN_EPS);
    float a = rs * g[j];
    A[j] = a;
    B[j] = bt[j] - m * a;
}

// ---------------- launch ----------------

static inline char* alignp(char* p, size_t a) {
    return (char*)(((uintptr_t)p + a - 1) & ~(uintptr_t)(a - 1));
}

extern "C" void kernel_launch(void* const* d_in, const int* in_sizes, int n_in,
                              void* d_out, int out_size, void* d_ws, size_t ws_size,
                              hipStream_t stream) {
    const float* x   = (const float*)d_in[0];
    const int*   ei  = (const int*)d_in[1];
    const float* ea  = (const float*)d_in[2];
    const float* Wp[3]  = {(const float*)d_in[3],  (const float*)d_in[9],  (const float*)d_in[15]};
    const float* bp[3]  = {(const float*)d_in[4],  (const float*)d_in[10], (const float*)d_in[16]};
    const float* Wep[3] = {(const float*)d_in[5],  (const float*)d_in[11], (const float*)d_in[17]};
    const float* bep[3] = {(const float*)d_in[6],  (const float*)d_in[12], (const float*)d_in[18]};
    const float* gp[3]  = {(const float*)d_in[7],  (const float*)d_in[13], (const float*)d_in[19]};
    const float* btp[3] = {(const float*)d_in[8],  (const float*)d_in[14], (const float*)d_in[20]};
    const float* Wl  = (const float*)d_in[21];
    const float* bl  = (const float*)d_in[22];
    float* out = (float*)d_out;

    char* p = (char*)d_ws;
    auto alloc = [&](size_t bytes) -> void* {
        p = alignp(p, 256);
        void* r = (void*)p;
        p += bytes;
        return r;
    };

    int*    deg_row  = (int*)alloc(NN * sizeof(int));
    int*    cnt_col  = (int*)alloc(NN * sizeof(int));
    int*    cursor   = (int*)alloc(NN * sizeof(int));
    int*    offs     = (int*)alloc((NN + 1) * sizeof(int));
    int*    bsum     = (int*)alloc(512 * sizeof(int));
    int*    bofs     = (int*)alloc(512 * sizeof(int));
    float*  dinv     = (float*)alloc(NN * sizeof(float));
    int*    csr_row  = (int*)alloc((size_t)NE * sizeof(int));
    float4* csr_meta = (float4*)alloc((size_t)NE * sizeof(float4));
    ushort* h_bf     = (ushort*)alloc((size_t)NN * DIM * sizeof(ushort));
    float*  t        = (float*)alloc((size_t)NN * DIM * sizeof(float));
    float*  Weff     = (float*)alloc(DIM * DIM * sizeof(float));
    float*  beff     = (float*)alloc(DIM * sizeof(float));
    float*  Av       = (float*)alloc(DIM * sizeof(float));
    float*  Bv       = (float*)alloc(DIM * sizeof(float));
    float*  stats    = (float*)alloc(2 * DIM * sizeof(float));

    const int NB_E = (NE + 255) / 256;
    const int NB_N = (NN + 255) / 256;

    hipMemsetAsync(deg_row, 0, NN * sizeof(int), stream);
    hipMemsetAsync(cnt_col, 0, NN * sizeof(int), stream);
    k_hist<<<NB_E, 256, 0, stream>>>(ei, deg_row, cnt_col);
    k_dinv<<<NB_N, 256, 0, stream>>>(deg_row, dinv);
    k_scan1<<<NB_N, 256, 0, stream>>>(cnt_col, offs, bsum);
    k_scan2<<<1, 512, 0, stream>>>(bsum, bofs, NB_N);
    k_scan3<<<NB_N, 256, 0, stream>>>(offs, bofs, cursor);
    k_fill<<<NB_E, 256, 0, stream>>>(ei, ea, dinv, cursor, csr_row, csr_meta);

    k_initAB<<<1, 128, 0, stream>>>(Av, Bv);

    const float* Xin = x;
    for (int l = 0; l < 3; ++l) {
        k_prep_w<<<128, 128, 0, stream>>>(Wp[l], Av, Weff);
        k_prep_b<<<128, 128, 0, stream>>>(Wp[l], bp[l], Bv, beff, stats);
        k_gemm_bf<<<NN / 32, 256, 0, stream>>>(Xin, Weff, beff, h_bf);
        k_agg<<<NN / 4, 256, 0, stream>>>((const uint*)h_bf, csr_row, csr_meta, offs,
                                          Wep[l], bep[l], t);
        k_stats<<<256, 256, 0, stream>>>(t, stats);
        k_coeff<<<1, 128, 0, stream>>>(stats, gp[l], btp[l], Av, Bv);
        Xin = t;
    }

    k_prep_w<<<128, 128, 0, stream>>>(Wl, Av, Weff);
    k_prep_b<<<128, 128, 0, stream>>>(Wl, bl, Bv, beff, stats);
    k_gemm<<<NN / 32, 256, 0, stream>>>(t, Weff, beff, out);
}

// Round 3
// 1184.018 us; speedup vs baseline: 1.2957x; 1.0744x over previous
//
#include <hip/hip_runtime.h>
#include <stdint.h>

#define NN 100000
#define NE 1600000
#define DIM 128
#define BN_EPS 1e-5f

typedef unsigned int uint;
typedef unsigned short ushort;

// ---------------- bf16 helpers ----------------

static __device__ __forceinline__ ushort f2bf(float f) {
    uint u = __float_as_uint(f);
    u += 0x7FFF + ((u >> 16) & 1);   // round-to-nearest-even
    return (ushort)(u >> 16);
}
static __device__ __forceinline__ float bf_lo(uint p) {   // low 16 bits -> float
    return __uint_as_float(p << 16);
}
static __device__ __forceinline__ float bf_hi(uint p) {   // high 16 bits -> float
    return __uint_as_float(p & 0xFFFF0000u);
}

// ---------------- setup: degree histogram, dinv, CSR build ----------------

__global__ __launch_bounds__(256) void k_hist(const int* __restrict__ ei,
                                              int* __restrict__ deg_row,
                                              int* __restrict__ cnt_col) {
    int e = blockIdx.x * 256 + threadIdx.x;
    if (e < NE) {
        atomicAdd(&deg_row[ei[e]], 1);
        atomicAdd(&cnt_col[ei[NE + e]], 1);
    }
}

__global__ __launch_bounds__(256) void k_dinv(const int* __restrict__ deg_row,
                                              float* __restrict__ dinv) {
    int v = blockIdx.x * 256 + threadIdx.x;
    if (v < NN) dinv[v] = rsqrtf((float)deg_row[v] + 1.0f);
}

__global__ __launch_bounds__(256) void k_scan1(const int* __restrict__ cnt,
                                               int* __restrict__ offs,
                                               int* __restrict__ bsum) {
    __shared__ int s[256];
    int t = threadIdx.x;
    int i = blockIdx.x * 256 + t;
    int v = (i < NN) ? cnt[i] : 0;
    s[t] = v;
    __syncthreads();
    for (int d = 1; d < 256; d <<= 1) {
        int add = (t >= d) ? s[t - d] : 0;
        __syncthreads();
        s[t] += add;
        __syncthreads();
    }
    if (i < NN) offs[i] = s[t] - v;
    if (t == 255) bsum[blockIdx.x] = s[t];
}

__global__ __launch_bounds__(512) void k_scan2(const int* __restrict__ bsum,
                                               int* __restrict__ bofs, int nb) {
    __shared__ int s[512];
    int t = threadIdx.x;
    int v = (t < nb) ? bsum[t] : 0;
    s[t] = v;
    __syncthreads();
    for (int d = 1; d < 512; d <<= 1) {
        int add = (t >= d) ? s[t - d] : 0;
        __syncthreads();
        s[t] += add;
        __syncthreads();
    }
    if (t < nb) bofs[t] = s[t] - v;
}

__global__ __launch_bounds__(256) void k_scan3(int* __restrict__ offs,
                                               const int* __restrict__ bofs,
                                               int* __restrict__ cursor) {
    int i = blockIdx.x * 256 + threadIdx.x;
    if (i < NN) {
        int o = offs[i] + bofs[blockIdx.x];
        offs[i] = o;
        cursor[i] = o;
    }
    if (i == 0) offs[NN] = NE;
}

// one packed 16B record per edge: {norm, bf16(ea0)|bf16(ea1), bf16(ea2)|0, row}
__global__ __launch_bounds__(256) void k_fill(const int* __restrict__ ei,
                                              const float* __restrict__ ea,
                                              const float* __restrict__ dinv,
                                              int* __restrict__ cursor,
                                              float4* __restrict__ csr) {
    int e = blockIdx.x * 256 + threadIdx.x;
    if (e < NE) {
        int r = ei[e];
        int c = ei[NE + e];
        int p = atomicAdd(&cursor[c], 1);
        float4 rec;
        rec.x = dinv[r] * dinv[c];
        rec.y = __uint_as_float(((uint)f2bf(ea[e * 3]) << 16) | (uint)f2bf(ea[e * 3 + 1]));
        rec.z = __uint_as_float((uint)f2bf(ea[e * 3 + 2]) << 16);
        rec.w = __int_as_float(r);
        csr[p] = rec;
    }
}

// ---------------- BN folding helpers ----------------

__global__ void k_initAB(float* __restrict__ A, float* __restrict__ B) {
    int j = threadIdx.x;
    A[j] = 1.0f;
    B[j] = 0.0f;
}

__global__ __launch_bounds__(128) void k_prep_w(const float* __restrict__ W,
                                                const float* __restrict__ A,
                                                float* __restrict__ Weff) {
    int k = blockIdx.x, j = threadIdx.x;
    Weff[k * DIM + j] = A[k] * W[k * DIM + j];
}

__global__ __launch_bounds__(128) void k_prep_b(const float* __restrict__ W,
                                                const float* __restrict__ b,
                                                const float* __restrict__ Bv,
                                                float* __restrict__ beff,
                                                float* __restrict__ stats) {
    int j = blockIdx.x, k = threadIdx.x;
    __shared__ float s[128];
    s[k] = Bv[k] * W[k * DIM + j];
    __syncthreads();
    for (int d = 64; d > 0; d >>= 1) {
        if (k < d) s[k] += s[k + d];
        __syncthreads();
    }
    if (k == 0) {
        beff[j] = b[j] + s[0];
        stats[j] = 0.0f;
        stats[DIM + j] = 0.0f;
    }
}

// ---------------- GEMM: Y[M,128] = X[M,128] @ W[128,128] + b ----------------

__device__ __forceinline__ void fma4(float4& a, float s, const float4& w) {
    a.x = fmaf(s, w.x, a.x);
    a.y = fmaf(s, w.y, a.y);
    a.z = fmaf(s, w.z, a.z);
    a.w = fmaf(s, w.w, a.w);
}

#define GEMM_BODY                                                                 \
    int tid = threadIdx.x;                                                        \
    int c4 = (tid & 31) * 4;                                                      \
    int rg = tid >> 5;                                                            \
    int r0 = blockIdx.x * 32 + rg * 4;                                            \
    float4 acc0 = {0, 0, 0, 0}, acc1 = {0, 0, 0, 0};                              \
    float4 acc2 = {0, 0, 0, 0}, acc3 = {0, 0, 0, 0};                              \
    const float* x0 = X + (size_t)r0 * DIM;                                       \
    for (int k = 0; k < DIM; k += 4) {                                            \
        float4 w0 = *(const float4*)&W[(k + 0) * DIM + c4];                       \
        float4 w1 = *(const float4*)&W[(k + 1) * DIM + c4];                       \
        float4 w2 = *(const float4*)&W[(k + 2) * DIM + c4];                       \
        float4 w3 = *(const float4*)&W[(k + 3) * DIM + c4];                       \
        float4 xa = *(const float4*)&x0[0 * DIM + k];                             \
        float4 xb = *(const float4*)&x0[1 * DIM + k];                             \
        float4 xc = *(const float4*)&x0[2 * DIM + k];                             \
        float4 xd = *(const float4*)&x0[3 * DIM + k];                             \
        fma4(acc0, xa.x, w0); fma4(acc0, xa.y, w1); fma4(acc0, xa.z, w2); fma4(acc0, xa.w, w3); \
        fma4(acc1, xb.x, w0); fma4(acc1, xb.y, w1); fma4(acc1, xb.z, w2); fma4(acc1, xb.w, w3); \
        fma4(acc2, xc.x, w0); fma4(acc2, xc.y, w1); fma4(acc2, xc.z, w2); fma4(acc2, xc.w, w3); \
        fma4(acc3, xd.x, w0); fma4(acc3, xd.y, w1); fma4(acc3, xd.z, w2); fma4(acc3, xd.w, w3); \
    }                                                                             \
    float4 bb = *(const float4*)&b[c4];                                           \
    acc0.x += bb.x; acc0.y += bb.y; acc0.z += bb.z; acc0.w += bb.w;               \
    acc1.x += bb.x; acc1.y += bb.y; acc1.z += bb.z; acc1.w += bb.w;               \
    acc2.x += bb.x; acc2.y += bb.y; acc2.z += bb.z; acc2.w += bb.w;               \
    acc3.x += bb.x; acc3.y += bb.y; acc3.z += bb.z; acc3.w += bb.w;

__global__ __launch_bounds__(256) void k_gemm(const float* __restrict__ X,
                                              const float* __restrict__ W,
                                              const float* __restrict__ b,
                                              float* __restrict__ Y) {
    GEMM_BODY
    *(float4*)&Y[(size_t)(r0 + 0) * DIM + c4] = acc0;
    *(float4*)&Y[(size_t)(r0 + 1) * DIM + c4] = acc1;
    *(float4*)&Y[(size_t)(r0 + 2) * DIM + c4] = acc2;
    *(float4*)&Y[(size_t)(r0 + 3) * DIM + c4] = acc3;
}

__global__ __launch_bounds__(256) void k_gemm_bf(const float* __restrict__ X,
                                                 const float* __restrict__ W,
                                                 const float* __restrict__ b,
                                                 ushort* __restrict__ Y) {
    GEMM_BODY
    ushort4 p0 = {f2bf(acc0.x), f2bf(acc0.y), f2bf(acc0.z), f2bf(acc0.w)};
    ushort4 p1 = {f2bf(acc1.x), f2bf(acc1.y), f2bf(acc1.z), f2bf(acc1.w)};
    ushort4 p2 = {f2bf(acc2.x), f2bf(acc2.y), f2bf(acc2.z), f2bf(acc2.w)};
    ushort4 p3 = {f2bf(acc3.x), f2bf(acc3.y), f2bf(acc3.z), f2bf(acc3.w)};
    *(ushort4*)&Y[(size_t)(r0 + 0) * DIM + c4] = p0;
    *(ushort4*)&Y[(size_t)(r0 + 1) * DIM + c4] = p1;
    *(ushort4*)&Y[(size_t)(r0 + 2) * DIM + c4] = p2;
    *(ushort4*)&Y[(size_t)(r0 + 3) * DIM + c4] = p3;
}

// ---------------- aggregation ----------------
// one wave per destination node; 4 edges per load instruction:
//   lane = q*16 + oc   (q = edge-in-group, oc = col-octet)
//   each lane gathers 16 B (8 bf16 cols) of edge q's source row.
// CSR is padded with 8 zero records; norm=0 masks tail/overrun contributions.

__global__ __launch_bounds__(256) void k_agg(const float4* __restrict__ h4,
                                             const float4* __restrict__ csr,
                                             const int* __restrict__ offs,
                                             const float* __restrict__ We,
                                             const float* __restrict__ be,
                                             float* __restrict__ t) {
    int wave = threadIdx.x >> 6;
    int lane = threadIdx.x & 63;
    int v = blockIdx.x * 4 + wave;
    if (v >= NN) return;
    int q  = lane >> 4;        // 0..3: which edge of the group
    int oc = lane & 15;        // 0..15: which col-octet
    int j0 = oc * 8;

    float4 w0a = *(const float4*)&We[j0];
    float4 w0b = *(const float4*)&We[j0 + 4];
    float4 w1a = *(const float4*)&We[DIM + j0];
    float4 w1b = *(const float4*)&We[DIM + j0 + 4];
    float4 w2a = *(const float4*)&We[2 * DIM + j0];
    float4 w2b = *(const float4*)&We[2 * DIM + j0 + 4];
    float4 bea = *(const float4*)&be[j0];
    float4 beb = *(const float4*)&be[j0 + 4];

    float4 accA = {0, 0, 0, 0}, accB = {0, 0, 0, 0};

    int s0 = offs[v], e0 = offs[v + 1];

    for (int base = s0; base < e0; base += 8) {
        int i1 = base + q;
        int i2 = base + 4 + q;
        float4 r1 = csr[i1];
        float4 r2 = csr[i2];
        int row1 = __float_as_int(r1.w);
        int row2 = __float_as_int(r2.w);
        float4 hv1 = h4[(size_t)row1 * 16 + oc];
        float4 hv2 = h4[(size_t)row2 * 16 + oc];
        float n1 = (i1 < e0) ? r1.x : 0.0f;
        float n2 = (i2 < e0) ? r2.x : 0.0f;

        {
            uint py = __float_as_uint(r1.y), pz = __float_as_uint(r1.z);
            float a0 = bf_hi(py), a1 = bf_lo(py), a2 = bf_hi(pz);
            float4 eA, eB;
            eA.x = fmaf(a0, w0a.x, fmaf(a1, w1a.x, fmaf(a2, w2a.x, bea.x)));
            eA.y = fmaf(a0, w0a.y, fmaf(a1, w1a.y, fmaf(a2, w2a.y, bea.y)));
            eA.z = fmaf(a0, w0a.z, fmaf(a1, w1a.z, fmaf(a2, w2a.z, bea.z)));
            eA.w = fmaf(a0, w0a.w, fmaf(a1, w1a.w, fmaf(a2, w2a.w, bea.w)));
            eB.x = fmaf(a0, w0b.x, fmaf(a1, w1b.x, fmaf(a2, w2b.x, beb.x)));
            eB.y = fmaf(a0, w0b.y, fmaf(a1, w1b.y, fmaf(a2, w2b.y, beb.y)));
            eB.z = fmaf(a0, w0b.z, fmaf(a1, w1b.z, fmaf(a2, w2b.z, beb.z)));
            eB.w = fmaf(a0, w0b.w, fmaf(a1, w1b.w, fmaf(a2, w2b.w, beb.w)));
            uint hx = __float_as_uint(hv1.x), hy = __float_as_uint(hv1.y);
            uint hz = __float_as_uint(hv1.z), hw = __float_as_uint(hv1.w);
            accA.x = fmaf(n1, fmaxf(bf_lo(hx) + eA.x, 0.f), accA.x);
            accA.y = fmaf(n1, fmaxf(bf_hi(hx) + eA.y, 0.f), accA.y);
            accA.z = fmaf(n1, fmaxf(bf_lo(hy) + eA.z, 0.f), accA.z);
            accA.w = fmaf(n1, fmaxf(bf_hi(hy) + eA.w, 0.f), accA.w);
            accB.x = fmaf(n1, fmaxf(bf_lo(hz) + eB.x, 0.f), accB.x);
            accB.y = fmaf(n1, fmaxf(bf_hi(hz) + eB.y, 0.f), accB.y);
            accB.z = fmaf(n1, fmaxf(bf_lo(hw) + eB.z, 0.f), accB.z);
            accB.w = fmaf(n1, fmaxf(bf_hi(hw) + eB.w, 0.f), accB.w);
        }
        {
            uint py = __float_as_uint(r2.y), pz = __float_as_uint(r2.z);
            float a0 = bf_hi(py), a1 = bf_lo(py), a2 = bf_hi(pz);
            float4 eA, eB;
            eA.x = fmaf(a0, w0a.x, fmaf(a1, w1a.x, fmaf(a2, w2a.x, bea.x)));
            eA.y = fmaf(a0, w0a.y, fmaf(a1, w1a.y, fmaf(a2, w2a.y, bea.y)));
            eA.z = fmaf(a0, w0a.z, fmaf(a1, w1a.z, fmaf(a2, w2a.z, bea.z)));
            eA.w = fmaf(a0, w0a.w, fmaf(a1, w1a.w, fmaf(a2, w2a.w, bea.w)));
            eB.x = fmaf(a0, w0b.x, fmaf(a1, w1b.x, fmaf(a2, w2b.x, beb.x)));
            eB.y = fmaf(a0, w0b.y, fmaf(a1, w1b.y, fmaf(a2, w2b.y, beb.y)));
            eB.z = fmaf(a0, w0b.z, fmaf(a1, w1b.z, fmaf(a2, w2b.z, beb.z)));
            eB.w = fmaf(a0, w0b.w, fmaf(a1, w1b.w, fmaf(a2, w2b.w, beb.w)));
            uint hx = __float_as_uint(hv2.x), hy = __float_as_uint(hv2.y);
            uint hz = __float_as_uint(hv2.z), hw = __float_as_uint(hv2.w);
            accA.x = fmaf(n2, fmaxf(bf_lo(hx) + eA.x, 0.f), accA.x);
            accA.y = fmaf(n2, fmaxf(bf_hi(hx) + eA.y, 0.f), accA.y);
            accA.z = fmaf(n2, fmaxf(bf_lo(hy) + eA.z, 0.f), accA.z);
            accA.w = fmaf(n2, fmaxf(bf_hi(hy) + eA.w, 0.f), accA.w);
            accB.x = fmaf(n2, fmaxf(bf_lo(hz) + eB.x, 0.f), accB.x);
            accB.y = fmaf(n2, fmaxf(bf_hi(hz) + eB.y, 0.f), accB.y);
            accB.z = fmaf(n2, fmaxf(bf_lo(hw) + eB.z, 0.f), accB.z);
            accB.w = fmaf(n2, fmaxf(bf_hi(hw) + eB.w, 0.f), accB.w);
        }
    }

    // reduce across the 4 edge-quads (lanes with equal oc)
    accA.x += __shfl_xor(accA.x, 16); accA.x += __shfl_xor(accA.x, 32);
    accA.y += __shfl_xor(accA.y, 16); accA.y += __shfl_xor(accA.y, 32);
    accA.z += __shfl_xor(accA.z, 16); accA.z += __shfl_xor(accA.z, 32);
    accA.w += __shfl_xor(accA.w, 16); accA.w += __shfl_xor(accA.w, 32);
    accB.x += __shfl_xor(accB.x, 16); accB.x += __shfl_xor(accB.x, 32);
    accB.y += __shfl_xor(accB.y, 16); accB.y += __shfl_xor(accB.y, 32);
    accB.z += __shfl_xor(accB.z, 16); accB.z += __shfl_xor(accB.z, 32);
    accB.w += __shfl_xor(accB.w, 16); accB.w += __shfl_xor(accB.w, 32);

    if (q == 0) {
        float4 oA, oB;
        oA.x = fmaxf(accA.x, 0.f); oA.y = fmaxf(accA.y, 0.f);
        oA.z = fmaxf(accA.z, 0.f); oA.w = fmaxf(accA.w, 0.f);
        oB.x = fmaxf(accB.x, 0.f); oB.y = fmaxf(accB.y, 0.f);
        oB.z = fmaxf(accB.z, 0.f); oB.w = fmaxf(accB.w, 0.f);
        *(float4*)&t[(size_t)v * DIM + j0] = oA;
        *(float4*)&t[(size_t)v * DIM + j0 + 4] = oB;
    }
}

// ---------------- BN statistics over t ----------------

__global__ __launch_bounds__(256) void k_stats(const float* __restrict__ t,
                                               float* __restrict__ stats) {
    int j = threadIdx.x & 127;
    int half = threadIdx.x >> 7;
    float s = 0.0f, q = 0.0f;
    for (int r = blockIdx.x * 2 + half; r < NN; r += 512) {
        float v = t[(size_t)r * DIM + j];
        s += v;
        q = fmaf(v, v, q);
    }
    __shared__ float ls[256], lq[256];
    ls[threadIdx.x] = s;
    lq[threadIdx.x] = q;
    __syncthreads();
    if (half == 0) {
        s += ls[threadIdx.x + 128];
        q += lq[threadIdx.x + 128];
        atomicAdd(&stats[j], s);
        atomicAdd(&stats[DIM + j], q);
    }
}

__global__ void k_coeff(const float* __restrict__ stats,
                        const float* __restrict__ g,
                        const float* __restrict__ bt,
                        float* __restrict__ A, float* __restrict__ B) {
    int j = threadIdx.x;
    float m = stats[j] * (1.0f / NN);
    float var = stats[DIM + j] * (1.0f / NN) - m * m;
    float rs = rsqrtf(var + BN_EPS);
    float a = rs * g[j];
    A[j] = a;
    B[j] = bt[j] - m * a;
}

// ---------------- launch ----------------

static inline char* alignp(char* p, size_t a) {
    return (char*)(((uintptr_t)p + a - 1) & ~(uintptr_t)(a - 1));
}

extern "C" void kernel_launch(void* const* d_in, const int* in_sizes, int n_in,
                              void* d_out, int out_size, void* d_ws, size_t ws_size,
                              hipStream_t stream) {
    const float* x   = (const float*)d_in[0];
    const int*   ei  = (const int*)d_in[1];
    const float* ea  = (const float*)d_in[2];
    const float* Wp[3]  = {(const float*)d_in[3],  (const float*)d_in[9],  (const float*)d_in[15]};
    const float* bp[3]  = {(const float*)d_in[4],  (const float*)d_in[10], (const float*)d_in[16]};
    const float* Wep[3] = {(const float*)d_in[5],  (const float*)d_in[11], (const float*)d_in[17]};
    const float* bep[3] = {(const float*)d_in[6],  (const float*)d_in[12], (const float*)d_in[18]};
    const float* gp[3]  = {(const float*)d_in[7],  (const float*)d_in[13], (const float*)d_in[19]};
    const float* btp[3] = {(const float*)d_in[8],  (const float*)d_in[14], (const float*)d_in[20]};
    const float* Wl  = (const float*)d_in[21];
    const float* bl  = (const float*)d_in[22];
    float* out = (float*)d_out;

    char* p = (char*)d_ws;
    auto alloc = [&](size_t bytes) -> void* {
        p = alignp(p, 256);
        void* r = (void*)p;
        p += bytes;
        return r;
    };

    int*    deg_row  = (int*)alloc(NN * sizeof(int));
    int*    cnt_col  = (int*)alloc(NN * sizeof(int));
    int*    cursor   = (int*)alloc(NN * sizeof(int));
    int*    offs     = (int*)alloc((NN + 1) * sizeof(int));
    int*    bsum     = (int*)alloc(512 * sizeof(int));
    int*    bofs     = (int*)alloc(512 * sizeof(int));
    float*  dinv     = (float*)alloc(NN * sizeof(float));
    float4* csr      = (float4*)alloc(((size_t)NE + 8) * sizeof(float4));
    ushort* h_bf     = (ushort*)alloc((size_t)NN * DIM * sizeof(ushort));
    float*  t        = (float*)alloc((size_t)NN * DIM * sizeof(float));
    float*  Weff     = (float*)alloc(DIM * DIM * sizeof(float));
    float*  beff     = (float*)alloc(DIM * sizeof(float));
    float*  Av       = (float*)alloc(DIM * sizeof(float));
    float*  Bv       = (float*)alloc(DIM * sizeof(float));
    float*  stats    = (float*)alloc(2 * DIM * sizeof(float));

    const int NB_E = (NE + 255) / 256;
    const int NB_N = (NN + 255) / 256;

    hipMemsetAsync(deg_row, 0, NN * sizeof(int), stream);
    hipMemsetAsync(cnt_col, 0, NN * sizeof(int), stream);
    hipMemsetAsync(csr + NE, 0, 8 * sizeof(float4), stream);   // zero-norm pad
    k_hist<<<NB_E, 256, 0, stream>>>(ei, deg_row, cnt_col);
    k_dinv<<<NB_N, 256, 0, stream>>>(deg_row, dinv);
    k_scan1<<<NB_N, 256, 0, stream>>>(cnt_col, offs, bsum);
    k_scan2<<<1, 512, 0, stream>>>(bsum, bofs, NB_N);
    k_scan3<<<NB_N, 256, 0, stream>>>(offs, bofs, cursor);
    k_fill<<<NB_E, 256, 0, stream>>>(ei, ea, dinv, cursor, csr);

    k_initAB<<<1, 128, 0, stream>>>(Av, Bv);

    const float* Xin = x;
    for (int l = 0; l < 3; ++l) {
        k_prep_w<<<128, 128, 0, stream>>>(Wp[l], Av, Weff);
        k_prep_b<<<128, 128, 0, stream>>>(Wp[l], bp[l], Bv, beff, stats);
        k_gemm_bf<<<NN / 32, 256, 0, stream>>>(Xin, Weff, beff, h_bf);
        k_agg<<<NN / 4, 256, 0, stream>>>((const float4*)h_bf, csr, offs,
                                          Wep[l], bep[l], t);
        k_stats<<<256, 256, 0, stream>>>(t, stats);
        k_coeff<<<1, 128, 0, stream>>>(stats, gp[l], btp[l], Av, Bv);
        Xin = t;
    }

    k_prep_w<<<128, 128, 0, stream>>>(Wl, Av, Weff);
    k_prep_b<<<128, 128, 0, stream>>>(Wl, bl, Bv, beff, stats);
    k_gemm<<<NN / 32, 256, 0, stream>>>(t, Weff, beff, out);
}

// Round 4
// 940.728 us; speedup vs baseline: 1.6308x; 1.2586x over previous
//
#include <hip/hip_runtime.h>
#include <stdint.h>

#define NN 100000
#define NE 1600000
#define DIM 128
#define BN_EPS 1e-5f
#define NBLK_GEMM 1563          // ceil(100000/64)
#define NBLK_AGG 1563           // ceil(100000/64): 4 waves x 16 nodes
#define NWAVES_AGG (NBLK_AGG * 4)

typedef unsigned int uint;
typedef unsigned short ushort;
typedef __attribute__((ext_vector_type(8))) short short8;   // 8 x bf16 (4 VGPRs)
typedef __attribute__((ext_vector_type(4))) float f32x4;

// ---------------- bf16 helpers ----------------

static __device__ __forceinline__ ushort f2bf(float f) {
    uint u = __float_as_uint(f);
    u += 0x7FFF + ((u >> 16) & 1);   // round-to-nearest-even
    return (ushort)(u >> 16);
}
static __device__ __forceinline__ float bf_lo(uint p) { return __uint_as_float(p << 16); }
static __device__ __forceinline__ float bf_hi(uint p) { return __uint_as_float(p & 0xFFFF0000u); }

// ---------------- setup: degree histogram, dinv, CSR build ----------------

__global__ __launch_bounds__(256) void k_hist(const int* __restrict__ ei,
                                              int* __restrict__ deg_row,
                                              int* __restrict__ cnt_col) {
    int e = blockIdx.x * 256 + threadIdx.x;
    if (e < NE) {
        atomicAdd(&deg_row[ei[e]], 1);
        atomicAdd(&cnt_col[ei[NE + e]], 1);
    }
}

__global__ __launch_bounds__(256) void k_dinv(const int* __restrict__ deg_row,
                                              float* __restrict__ dinv) {
    int v = blockIdx.x * 256 + threadIdx.x;
    if (v < NN) dinv[v] = rsqrtf((float)deg_row[v] + 1.0f);
}

__global__ __launch_bounds__(256) void k_scan1(const int* __restrict__ cnt,
                                               int* __restrict__ offs,
                                               int* __restrict__ bsum) {
    __shared__ int s[256];
    int t = threadIdx.x;
    int i = blockIdx.x * 256 + t;
    int v = (i < NN) ? cnt[i] : 0;
    s[t] = v;
    __syncthreads();
    for (int d = 1; d < 256; d <<= 1) {
        int add = (t >= d) ? s[t - d] : 0;
        __syncthreads();
        s[t] += add;
        __syncthreads();
    }
    if (i < NN) offs[i] = s[t] - v;
    if (t == 255) bsum[blockIdx.x] = s[t];
}

__global__ __launch_bounds__(512) void k_scan2(const int* __restrict__ bsum,
                                               int* __restrict__ bofs, int nb) {
    __shared__ int s[512];
    int t = threadIdx.x;
    int v = (t < nb) ? bsum[t] : 0;
    s[t] = v;
    __syncthreads();
    for (int d = 1; d < 512; d <<= 1) {
        int add = (t >= d) ? s[t - d] : 0;
        __syncthreads();
        s[t] += add;
        __syncthreads();
    }
    if (t < nb) bofs[t] = s[t] - v;
}

__global__ __launch_bounds__(256) void k_scan3(int* __restrict__ offs,
                                               const int* __restrict__ bofs,
                                               int* __restrict__ cursor) {
    int i = blockIdx.x * 256 + threadIdx.x;
    if (i < NN) {
        int o = offs[i] + bofs[blockIdx.x];
        offs[i] = o;
        cursor[i] = o;
    }
    if (i == 0) offs[NN] = NE;
}

// one packed 16B record per edge: {norm, bf16(ea0)|bf16(ea1), bf16(ea2)|0, row}
__global__ __launch_bounds__(256) void k_fill(const int* __restrict__ ei,
                                              const float* __restrict__ ea,
                                              const float* __restrict__ dinv,
                                              int* __restrict__ cursor,
                                              float4* __restrict__ csr) {
    int e = blockIdx.x * 256 + threadIdx.x;
    if (e < NE) {
        int r = ei[e];
        int c = ei[NE + e];
        int p = atomicAdd(&cursor[c], 1);
        float4 rec;
        rec.x = dinv[r] * dinv[c];
        rec.y = __uint_as_float(((uint)f2bf(ea[e * 3]) << 16) | (uint)f2bf(ea[e * 3 + 1]));
        rec.z = __uint_as_float((uint)f2bf(ea[e * 3 + 2]) << 16);
        rec.w = __int_as_float(r);
        csr[p] = rec;
    }
}

// ---------------- fp32 -> bf16 convert (input x, once) ----------------

__global__ __launch_bounds__(256) void k_x2bf(const float* __restrict__ x,
                                              ushort* __restrict__ xb) {
    int i = blockIdx.x * 256 + threadIdx.x;     // one float4 per thread
    float4 v = *(const float4*)&x[(size_t)i * 4];
    ushort4 o = {f2bf(v.x), f2bf(v.y), f2bf(v.z), f2bf(v.w)};
    *(ushort4*)&xb[(size_t)i * 4] = o;
}

// ---------------- BN folding helpers ----------------

__global__ void k_initAB(float* __restrict__ A, float* __restrict__ B) {
    int j = threadIdx.x;
    A[j] = 1.0f;
    B[j] = 0.0f;
}

// Wt[n][k] = bf16( A[k] * W[k][n] )  (transposed for MFMA B-fragment loads)
__global__ __launch_bounds__(128) void k_prep_wT(const float* __restrict__ W,
                                                 const float* __restrict__ A,
                                                 ushort* __restrict__ Wt) {
    int n = blockIdx.x, k = threadIdx.x;
    Wt[n * DIM + k] = f2bf(A[k] * W[k * DIM + n]);
}

// b_eff[j] = b[j] + sum_k B[k]*W[k][j]; also zero the BN stats accumulators
__global__ __launch_bounds__(128) void k_prep_b(const float* __restrict__ W,
                                                const float* __restrict__ b,
                                                const float* __restrict__ Bv,
                                                float* __restrict__ beff,
                                                float* __restrict__ stats) {
    int j = blockIdx.x, k = threadIdx.x;
    __shared__ float s[128];
    s[k] = Bv[k] * W[k * DIM + j];
    __syncthreads();
    for (int d = 64; d > 0; d >>= 1) {
        if (k < d) s[k] += s[k + d];
        __syncthreads();
    }
    if (k == 0) {
        beff[j] = b[j] + s[0];
        stats[j] = 0.0f;
        stats[DIM + j] = 0.0f;
    }
}

// ---------------- MFMA GEMM: Y[M,128] = A_bf[M,128] @ W + beff ----------------
// block = 256 (4 waves), wave computes 16 rows x 128 cols via 8 col-tiles.
// A frag: lane = quad*16 + m reads A[row0+m][quad*8 .. +7] per K-step.
// B frag: Wt is N x K (transposed), lane reads Wt[nt*16+m][quad*8 .. +7].
// C/D: col = lane&15, row = quad*4 + reg  [measured: learn_hip m89/m91]

#define GEMM_MFMA_BODY(Abf, Wt)                                                     \
    const int lane = threadIdx.x & 63;                                              \
    const int wv   = threadIdx.x >> 6;                                              \
    const int m    = lane & 15;                                                     \
    const int quad = lane >> 4;                                                     \
    const int row0 = blockIdx.x * 64 + wv * 16;                                     \
    const int rr   = min(row0 + m, NN - 1);                                         \
    const short8* ap = (const short8*)&Abf[(size_t)rr * DIM + quad * 8];            \
    short8 a0 = ap[0];                                                              \
    short8 a1 = ap[4];                                                              \
    short8 a2 = ap[8];                                                              \
    short8 a3 = ap[12];                                                             \
    f32x4 acc[8];                                                                   \
    _Pragma("unroll")                                                               \
    for (int nt = 0; nt < 8; ++nt) {                                                \
        const short8* bp = (const short8*)&Wt[(size_t)(nt * 16 + m) * DIM + quad * 8]; \
        f32x4 c = {0.f, 0.f, 0.f, 0.f};                                             \
        c = __builtin_amdgcn_mfma_f32_16x16x32_bf16(a0, bp[0],  c, 0, 0, 0);        \
        c = __builtin_amdgcn_mfma_f32_16x16x32_bf16(a1, bp[4],  c, 0, 0, 0);        \
        c = __builtin_amdgcn_mfma_f32_16x16x32_bf16(a2, bp[8],  c, 0, 0, 0);        \
        c = __builtin_amdgcn_mfma_f32_16x16x32_bf16(a3, bp[12], c, 0, 0, 0);        \
        acc[nt] = c;                                                                \
    }                                                                               \
    const int rbase = row0 + quad * 4;

// bf16 output (h for the gather)
__global__ __launch_bounds__(256) void k_gemm_mf_bf(const ushort* __restrict__ Abf,
                                                    const ushort* __restrict__ Wt,
                                                    const float* __restrict__ beff,
                                                    ushort* __restrict__ Y) {
    GEMM_MFMA_BODY(Abf, Wt)
#pragma unroll
    for (int nt = 0; nt < 8; ++nt) {
        int col = nt * 16 + m;
        float bb = beff[col];
#pragma unroll
        for (int i = 0; i < 4; ++i) {
            int row = rbase + i;
            if (row < NN) Y[(size_t)row * DIM + col] = f2bf(acc[nt][i] + bb);
        }
    }
}

// fp32 output (final linear -> d_out)
__global__ __launch_bounds__(256) void k_gemm_mf_f32(const ushort* __restrict__ Abf,
                                                     const ushort* __restrict__ Wt,
                                                     const float* __restrict__ beff,
                                                     float* __restrict__ Y) {
    GEMM_MFMA_BODY(Abf, Wt)
#pragma unroll
    for (int nt = 0; nt < 8; ++nt) {
        int col = nt * 16 + m;
        float bb = beff[col];
#pragma unroll
        for (int i = 0; i < 4; ++i) {
            int row = rbase + i;
            if (row < NN) Y[(size_t)row * DIM + col] = acc[nt][i] + bb;
        }
    }
}

// ---------------- aggregation + fused BN statistics ----------------
// wave processes 16 consecutive nodes; per node: 4 edges per load instruction
// (lane = q*16 + oc); CSR padded with 8 zero-norm records for the tail.
// t output is bf16; per-wave stat partials (sum, sumsq per col) -> partial[].

__global__ __launch_bounds__(256) void k_agg(const float4* __restrict__ h4,
                                             const float4* __restrict__ csr,
                                             const int* __restrict__ offs,
                                             const float* __restrict__ We,
                                             const float* __restrict__ be,
                                             uint* __restrict__ tb,      // bf16 pairs
                                             float* __restrict__ partial) {
    int wv = threadIdx.x >> 6;
    int lane = threadIdx.x & 63;
    int q  = lane >> 4;        // 0..3: edge slot in group
    int oc = lane & 15;        // 0..15: col-octet
    int j0 = oc * 8;

    float4 w0a = *(const float4*)&We[j0];
    float4 w0b = *(const float4*)&We[j0 + 4];
    float4 w1a = *(const float4*)&We[DIM + j0];
    float4 w1b = *(const float4*)&We[DIM + j0 + 4];
    float4 w2a = *(const float4*)&We[2 * DIM + j0];
    float4 w2b = *(const float4*)&We[2 * DIM + j0 + 4];
    float4 bea = *(const float4*)&be[j0];
    float4 beb = *(const float4*)&be[j0 + 4];

    float4 sm0 = {0, 0, 0, 0}, sm1 = {0, 0, 0, 0};   // col sums
    float4 sq0 = {0, 0, 0, 0}, sq1 = {0, 0, 0, 0};   // col sumsq

    for (int it = 0; it < 16; ++it) {
        int v = blockIdx.x * 64 + wv * 16 + it;
        if (v >= NN) break;

        float4 accA = {0, 0, 0, 0}, accB = {0, 0, 0, 0};
        int s0 = offs[v], e0 = offs[v + 1];

        for (int base = s0; base < e0; base += 8) {
            int i1 = base + q;
            int i2 = base + 4 + q;
            float4 r1 = csr[i1];
            float4 r2 = csr[i2];
            int row1 = __float_as_int(r1.w);
            int row2 = __float_as_int(r2.w);
            float4 hv1 = h4[(size_t)row1 * 16 + oc];
            float4 hv2 = h4[(size_t)row2 * 16 + oc];
            float n1 = (i1 < e0) ? r1.x : 0.0f;
            float n2 = (i2 < e0) ? r2.x : 0.0f;

            {
                uint py = __float_as_uint(r1.y), pz = __float_as_uint(r1.z);
                float a0 = bf_hi(py), a1 = bf_lo(py), a2 = bf_hi(pz);
                float4 eA, eB;
                eA.x = fmaf(a0, w0a.x, fmaf(a1, w1a.x, fmaf(a2, w2a.x, bea.x)));
                eA.y = fmaf(a0, w0a.y, fmaf(a1, w1a.y, fmaf(a2, w2a.y, bea.y)));
                eA.z = fmaf(a0, w0a.z, fmaf(a1, w1a.z, fmaf(a2, w2a.z, bea.z)));
                eA.w = fmaf(a0, w0a.w, fmaf(a1, w1a.w, fmaf(a2, w2a.w, bea.w)));
                eB.x = fmaf(a0, w0b.x, fmaf(a1, w1b.x, fmaf(a2, w2b.x, beb.x)));
                eB.y = fmaf(a0, w0b.y, fmaf(a1, w1b.y, fmaf(a2, w2b.y, beb.y)));
                eB.z = fmaf(a0, w0b.z, fmaf(a1, w1b.z, fmaf(a2, w2b.z, beb.z)));
                eB.w = fmaf(a0, w0b.w, fmaf(a1, w1b.w, fmaf(a2, w2b.w, beb.w)));
                uint hx = __float_as_uint(hv1.x), hy = __float_as_uint(hv1.y);
                uint hz = __float_as_uint(hv1.z), hw = __float_as_uint(hv1.w);
                accA.x = fmaf(n1, fmaxf(bf_lo(hx) + eA.x, 0.f), accA.x);
                accA.y = fmaf(n1, fmaxf(bf_hi(hx) + eA.y, 0.f), accA.y);
                accA.z = fmaf(n1, fmaxf(bf_lo(hy) + eA.z, 0.f), accA.z);
                accA.w = fmaf(n1, fmaxf(bf_hi(hy) + eA.w, 0.f), accA.w);
                accB.x = fmaf(n1, fmaxf(bf_lo(hz) + eB.x, 0.f), accB.x);
                accB.y = fmaf(n1, fmaxf(bf_hi(hz) + eB.y, 0.f), accB.y);
                accB.z = fmaf(n1, fmaxf(bf_lo(hw) + eB.z, 0.f), accB.z);
                accB.w = fmaf(n1, fmaxf(bf_hi(hw) + eB.w, 0.f), accB.w);
            }
            {
                uint py = __float_as_uint(r2.y), pz = __float_as_uint(r2.z);
                float a0 = bf_hi(py), a1 = bf_lo(py), a2 = bf_hi(pz);
                float4 eA, eB;
                eA.x = fmaf(a0, w0a.x, fmaf(a1, w1a.x, fmaf(a2, w2a.x, bea.x)));
                eA.y = fmaf(a0, w0a.y, fmaf(a1, w1a.y, fmaf(a2, w2a.y, bea.y)));
                eA.z = fmaf(a0, w0a.z, fmaf(a1, w1a.z, fmaf(a2, w2a.z, bea.z)));
                eA.w = fmaf(a0, w0a.w, fmaf(a1, w1a.w, fmaf(a2, w2a.w, bea.w)));
                eB.x = fmaf(a0, w0b.x, fmaf(a1, w1b.x, fmaf(a2, w2b.x, beb.x)));
                eB.y = fmaf(a0, w0b.y, fmaf(a1, w1b.y, fmaf(a2, w2b.y, beb.y)));
                eB.z = fmaf(a0, w0b.z, fmaf(a1, w1b.z, fmaf(a2, w2b.z, beb.z)));
                eB.w = fmaf(a0, w0b.w, fmaf(a1, w1b.w, fmaf(a2, w2b.w, beb.w)));
                uint hx = __float_as_uint(hv2.x), hy = __float_as_uint(hv2.y);
                uint hz = __float_as_uint(hv2.z), hw = __float_as_uint(hv2.w);
                accA.x = fmaf(n2, fmaxf(bf_lo(hx) + eA.x, 0.f), accA.x);
                accA.y = fmaf(n2, fmaxf(bf_hi(hx) + eA.y, 0.f), accA.y);
                accA.z = fmaf(n2, fmaxf(bf_lo(hy) + eA.z, 0.f), accA.z);
                accA.w = fmaf(n2, fmaxf(bf_hi(hy) + eA.w, 0.f), accA.w);
                accB.x = fmaf(n2, fmaxf(bf_lo(hz) + eB.x, 0.f), accB.x);
                accB.y = fmaf(n2, fmaxf(bf_hi(hz) + eB.y, 0.f), accB.y);
                accB.z = fmaf(n2, fmaxf(bf_lo(hw) + eB.z, 0.f), accB.z);
                accB.w = fmaf(n2, fmaxf(bf_hi(hw) + eB.w, 0.f), accB.w);
            }
        }

        // reduce across the 4 edge-quads (lanes with equal oc)
        accA.x += __shfl_xor(accA.x, 16); accA.x += __shfl_xor(accA.x, 32);
        accA.y += __shfl_xor(accA.y, 16); accA.y += __shfl_xor(accA.y, 32);
        accA.z += __shfl_xor(accA.z, 16); accA.z += __shfl_xor(accA.z, 32);
        accA.w += __shfl_xor(accA.w, 16); accA.w += __shfl_xor(accA.w, 32);
        accB.x += __shfl_xor(accB.x, 16); accB.x += __shfl_xor(accB.x, 32);
        accB.y += __shfl_xor(accB.y, 16); accB.y += __shfl_xor(accB.y, 32);
        accB.z += __shfl_xor(accB.z, 16); accB.z += __shfl_xor(accB.z, 32);
        accB.w += __shfl_xor(accB.w, 16); accB.w += __shfl_xor(accB.w, 32);

        if (q == 0) {
            float o0 = fmaxf(accA.x, 0.f), o1 = fmaxf(accA.y, 0.f);
            float o2 = fmaxf(accA.z, 0.f), o3 = fmaxf(accA.w, 0.f);
            float o4 = fmaxf(accB.x, 0.f), o5 = fmaxf(accB.y, 0.f);
            float o6 = fmaxf(accB.z, 0.f), o7 = fmaxf(accB.w, 0.f);
            sm0.x += o0; sm0.y += o1; sm0.z += o2; sm0.w += o3;
            sm1.x += o4; sm1.y += o5; sm1.z += o6; sm1.w += o7;
            sq0.x = fmaf(o0, o0, sq0.x); sq0.y = fmaf(o1, o1, sq0.y);
            sq0.z = fmaf(o2, o2, sq0.z); sq0.w = fmaf(o3, o3, sq0.w);
            sq1.x = fmaf(o4, o4, sq1.x); sq1.y = fmaf(o5, o5, sq1.y);
            sq1.z = fmaf(o6, o6, sq1.z); sq1.w = fmaf(o7, o7, sq1.w);
            uint4 pk;
            pk.x = ((uint)f2bf(o1) << 16) | f2bf(o0);
            pk.y = ((uint)f2bf(o3) << 16) | f2bf(o2);
            pk.z = ((uint)f2bf(o5) << 16) | f2bf(o4);
            pk.w = ((uint)f2bf(o7) << 16) | f2bf(o6);
            *(uint4*)&tb[(size_t)v * 64 + oc * 4] = pk;
        }
    }

    if (q == 0) {
        int w = blockIdx.x * 4 + wv;
        float* pp = &partial[(size_t)w * 256 + oc * 8];
        *(float4*)pp = sm0;
        *(float4*)(pp + 4) = sm1;
        *(float4*)(pp + 128) = sq0;
        *(float4*)(pp + 132) = sq1;
    }
}

// reduce per-wave partials into stats[256]
__global__ __launch_bounds__(256) void k_red(const float* __restrict__ partial,
                                             float* __restrict__ stats) {
    float s = 0.0f;
    for (int w = blockIdx.x; w < NWAVES_AGG; w += 64)
        s += partial[(size_t)w * 256 + threadIdx.x];
    atomicAdd(&stats[threadIdx.x], s);
}

__global__ void k_coeff(const float* __restrict__ stats,
                        const float* __restrict__ g,
                        const float* __restrict__ bt,
                        float* __restrict__ A, float* __restrict__ B) {
    int j = threadIdx.x;
    float m = stats[j] * (1.0f / NN);
    float var = stats[DIM + j] * (1.0f / NN) - m * m;
    float rs = rsqrtf(var + BN_EPS);
    float a = rs * g[j];
    A[j] = a;
    B[j] = bt[j] - m * a;
}

// ---------------- launch ----------------

static inline char* alignp(char* p, size_t a) {
    return (char*)(((uintptr_t)p + a - 1) & ~(uintptr_t)(a - 1));
}

extern "C" void kernel_launch(void* const* d_in, const int* in_sizes, int n_in,
                              void* d_out, int out_size, void* d_ws, size_t ws_size,
                              hipStream_t stream) {
    const float* x   = (const float*)d_in[0];
    const int*   ei  = (const int*)d_in[1];
    const float* ea  = (const float*)d_in[2];
    const float* Wp[3]  = {(const float*)d_in[3],  (const float*)d_in[9],  (const float*)d_in[15]};
    const float* bp[3]  = {(const float*)d_in[4],  (const float*)d_in[10], (const float*)d_in[16]};
    const float* Wep[3] = {(const float*)d_in[5],  (const float*)d_in[11], (const float*)d_in[17]};
    const float* bep[3] = {(const float*)d_in[6],  (const float*)d_in[12], (const float*)d_in[18]};
    const float* gp[3]  = {(const float*)d_in[7],  (const float*)d_in[13], (const float*)d_in[19]};
    const float* btp[3] = {(const float*)d_in[8],  (const float*)d_in[14], (const float*)d_in[20]};
    const float* Wl  = (const float*)d_in[21];
    const float* bl  = (const float*)d_in[22];
    float* out = (float*)d_out;

    char* p = (char*)d_ws;
    auto alloc = [&](size_t bytes) -> void* {
        p = alignp(p, 256);
        void* r = (void*)p;
        p += bytes;
        return r;
    };

    int*    deg_row  = (int*)alloc(NN * sizeof(int));
    int*    cnt_col  = (int*)alloc(NN * sizeof(int));
    int*    cursor   = (int*)alloc(NN * sizeof(int));
    int*    offs     = (int*)alloc((NN + 1) * sizeof(int));
    int*    bsum     = (int*)alloc(512 * sizeof(int));
    int*    bofs     = (int*)alloc(512 * sizeof(int));
    float*  dinv     = (float*)alloc(NN * sizeof(float));
    float4* csr      = (float4*)alloc(((size_t)NE + 8) * sizeof(float4));
    ushort* x_bf     = (ushort*)alloc((size_t)NN * DIM * sizeof(ushort));
    ushort* h_bf     = (ushort*)alloc((size_t)NN * DIM * sizeof(ushort));
    ushort* t_bf     = (ushort*)alloc((size_t)NN * DIM * sizeof(ushort));
    float*  partial  = (float*)alloc((size_t)NWAVES_AGG * 256 * sizeof(float));
    ushort* Wt       = (ushort*)alloc(DIM * DIM * sizeof(ushort));
    float*  beff     = (float*)alloc(DIM * sizeof(float));
    float*  Av       = (float*)alloc(DIM * sizeof(float));
    float*  Bv       = (float*)alloc(DIM * sizeof(float));
    float*  stats    = (float*)alloc(2 * DIM * sizeof(float));

    const int NB_E = (NE + 255) / 256;
    const int NB_N = (NN + 255) / 256;

    hipMemsetAsync(deg_row, 0, NN * sizeof(int), stream);
    hipMemsetAsync(cnt_col, 0, NN * sizeof(int), stream);
    hipMemsetAsync(csr + NE, 0, 8 * sizeof(float4), stream);   // zero-norm pad
    k_hist<<<NB_E, 256, 0, stream>>>(ei, deg_row, cnt_col);
    k_dinv<<<NB_N, 256, 0, stream>>>(deg_row, dinv);
    k_scan1<<<NB_N, 256, 0, stream>>>(cnt_col, offs, bsum);
    k_scan2<<<1, 512, 0, stream>>>(bsum, bofs, NB_N);
    k_scan3<<<NB_N, 256, 0, stream>>>(offs, bofs, cursor);
    k_fill<<<NB_E, 256, 0, stream>>>(ei, ea, dinv, cursor, csr);

    k_x2bf<<<NN * DIM / 4 / 256, 256, 0, stream>>>(x, x_bf);
    k_initAB<<<1, 128, 0, stream>>>(Av, Bv);

    const ushort* Xbf = x_bf;
    for (int l = 0; l < 3; ++l) {
        k_prep_wT<<<128, 128, 0, stream>>>(Wp[l], Av, Wt);
        k_prep_b<<<128, 128, 0, stream>>>(Wp[l], bp[l], Bv, beff, stats);
        k_gemm_mf_bf<<<NBLK_GEMM, 256, 0, stream>>>(Xbf, Wt, beff, h_bf);
        k_agg<<<NBLK_AGG, 256, 0, stream>>>((const float4*)h_bf, csr, offs,
                                            Wep[l], bep[l], (uint*)t_bf, partial);
        k_red<<<64, 256, 0, stream>>>(partial, stats);
        k_coeff<<<1, 128, 0, stream>>>(stats, gp[l], btp[l], Av, Bv);
        Xbf = t_bf;
    }

    k_prep_wT<<<128, 128, 0, stream>>>(Wl, Av, Wt);
    k_prep_b<<<128, 128, 0, stream>>>(Wl, bl, Bv, beff, stats);
    k_gemm_mf_f32<<<NBLK_GEMM, 256, 0, stream>>>(t_bf, Wt, beff, out);
}

// Round 5
// 866.338 us; speedup vs baseline: 1.7709x; 1.0859x over previous
//
#include <hip/hip_runtime.h>
#include <stdint.h>

#define NN 100000
#define NE 1600000
#define DIM 128
#define BN_EPS 1e-5f
#define NBUCK 391               // ceil(NN/256) col/row buckets of 256 nodes
#define NBLK_GEMM 1563          // ceil(100000/64)
#define NBLK_AGG 1563           // ceil(100000/64): 4 waves x 16 nodes
#define NWAVES_AGG (NBLK_AGG * 4)
#define NB_CNT 196              // ceil(NE/8192)
#define NB_SCC 391              // ceil(NE/4096)

typedef unsigned int uint;
typedef unsigned short ushort;
typedef unsigned char uchar;
typedef __attribute__((ext_vector_type(8))) short short8;   // 8 x bf16 (4 VGPRs)
typedef __attribute__((ext_vector_type(4))) float f32x4;

// ---------------- bf16 helpers ----------------

static __device__ __forceinline__ ushort f2bf(float f) {
    uint u = __float_as_uint(f);
    u += 0x7FFF + ((u >> 16) & 1);   // round-to-nearest-even
    return (ushort)(u >> 16);
}
static __device__ __forceinline__ float bf_lo(uint p) { return __uint_as_float(p << 16); }
static __device__ __forceinline__ float bf_hi(uint p) { return __uint_as_float(p & 0xFFFF0000u); }

// ============ setup: bucket-sort CSR build (no million-scale atomics) ============

// pass 1: coarse bucket counts for rows and cols (per-block LDS hist,
// one global atomic per non-empty bucket per block: ~150K total)
__global__ __launch_bounds__(256) void k_count(const int* __restrict__ ei,
                                               int* __restrict__ rowCnt,
                                               int* __restrict__ colCnt) {
    __shared__ int hr[NBUCK], hc[NBUCK];
    int tid = threadIdx.x;
    for (int b = tid; b < NBUCK; b += 256) { hr[b] = 0; hc[b] = 0; }
    __syncthreads();
    int e0 = blockIdx.x * 8192;
    int e1 = min(NE, e0 + 8192);
    for (int e = e0 + tid; e < e1; e += 256) {
        atomicAdd(&hr[ei[e] >> 8], 1);
        atomicAdd(&hc[ei[NE + e] >> 8], 1);
    }
    __syncthreads();
    for (int b = tid; b < NBUCK; b += 256) {
        if (hr[b]) atomicAdd(&rowCnt[b], hr[b]);
        if (hc[b]) atomicAdd(&colCnt[b], hc[b]);
    }
}

// scan bucket counts -> bases + cursors (both row and col), 1 block
__global__ __launch_bounds__(512) void k_scanb(const int* __restrict__ rowCnt,
                                               const int* __restrict__ colCnt,
                                               int* __restrict__ rowBase,
                                               int* __restrict__ colBase,
                                               int* __restrict__ rowCur,
                                               int* __restrict__ colCur) {
    __shared__ int s[512];
    int tid = threadIdx.x;
    // rows
    int v = (tid < NBUCK) ? rowCnt[tid] : 0;
    s[tid] = v;
    __syncthreads();
    for (int d = 1; d < 512; d <<= 1) {
        int a = (tid >= d) ? s[tid - d] : 0;
        __syncthreads();
        s[tid] += a;
        __syncthreads();
    }
    if (tid < NBUCK) { int e = s[tid] - v; rowBase[tid] = e; rowCur[tid] = e; }
    if (tid == NBUCK) rowBase[NBUCK] = s[NBUCK - 1 + 1] - 0;   // s[391] = total
    __syncthreads();
    // cols
    v = (tid < NBUCK) ? colCnt[tid] : 0;
    s[tid] = v;
    __syncthreads();
    for (int d = 1; d < 512; d <<= 1) {
        int a = (tid >= d) ? s[tid - d] : 0;
        __syncthreads();
        s[tid] += a;
        __syncthreads();
    }
    if (tid < NBUCK) { int e = s[tid] - v; colBase[tid] = e; colCur[tid] = e; }
    if (tid == NBUCK) colBase[NBUCK] = s[NBUCK - 1 + 1] - 0;
}

// scatter row fine-bytes into row-bucket regions
__global__ __launch_bounds__(256) void k_scat_row(const int* __restrict__ ei,
                                                  int* __restrict__ rowCur,
                                                  uchar* __restrict__ rowScat) {
    __shared__ int h[NBUCK], lb[NBUCK], lc[NBUCK];
    int tid = threadIdx.x;
    for (int b = tid; b < NBUCK; b += 256) { h[b] = 0; lc[b] = 0; }
    __syncthreads();
    int e0 = blockIdx.x * 8192;
    int e1 = min(NE, e0 + 8192);
    for (int e = e0 + tid; e < e1; e += 256) atomicAdd(&h[ei[e] >> 8], 1);
    __syncthreads();
    for (int b = tid; b < NBUCK; b += 256)
        lb[b] = h[b] ? atomicAdd(&rowCur[b], h[b]) : 0;
    __syncthreads();
    for (int e = e0 + tid; e < e1; e += 256) {
        int r = ei[e];
        int b = r >> 8;
        int pos = lb[b] + atomicAdd(&lc[b], 1);
        rowScat[pos] = (uchar)(r & 255);
    }
}

// per-bucket fine histogram of rows -> dinv directly
__global__ __launch_bounds__(256) void k_deg(const uchar* __restrict__ rowScat,
                                             const int* __restrict__ rowBase,
                                             float* __restrict__ dinv) {
    __shared__ int h[256];
    int tid = threadIdx.x;
    int b = blockIdx.x;
    h[tid] = 0;
    __syncthreads();
    int base = rowBase[b], cnt = rowBase[b + 1] - base;
    for (int i = tid; i < cnt; i += 256) atomicAdd(&h[rowScat[base + i]], 1);
    __syncthreads();
    int node = b * 256 + tid;
    if (node < NN) dinv[node] = rsqrtf((float)h[tid] + 1.0f);
}

// scatter full 16B CSR records into col-bucket regions (needs dinv ready)
// record: {norm, bf16(ea0)|bf16(ea1), bf16(ea2)|fine8, row}
__global__ __launch_bounds__(256) void k_scat_col(const int* __restrict__ ei,
                                                  const float* __restrict__ ea,
                                                  const float* __restrict__ dinv,
                                                  int* __restrict__ colCur,
                                                  uint4* __restrict__ tmp) {
    __shared__ int h[NBUCK], lb[NBUCK], lc[NBUCK];
    int tid = threadIdx.x;
    for (int b = tid; b < NBUCK; b += 256) { h[b] = 0; lc[b] = 0; }
    __syncthreads();
    int e0 = blockIdx.x * 4096;
    int e1 = min(NE, e0 + 4096);
    for (int e = e0 + tid; e < e1; e += 256) atomicAdd(&h[ei[NE + e] >> 8], 1);
    __syncthreads();
    for (int b = tid; b < NBUCK; b += 256)
        lb[b] = h[b] ? atomicAdd(&colCur[b], h[b]) : 0;
    __syncthreads();
    for (int e = e0 + tid; e < e1; e += 256) {
        int r = ei[e];
        int c = ei[NE + e];
        int b = c >> 8;
        int pos = lb[b] + atomicAdd(&lc[b], 1);
        uint4 rec;
        rec.x = __float_as_uint(dinv[r] * dinv[c]);
        rec.y = ((uint)f2bf(ea[e * 3]) << 16) | (uint)f2bf(ea[e * 3 + 1]);
        rec.z = ((uint)f2bf(ea[e * 3 + 2]) << 16) | (uint)(c & 255);
        rec.w = (uint)r;
        tmp[pos] = rec;
    }
}

// per-bucket fine counting sort -> final csr (contiguous writes) + offs directly
__global__ __launch_bounds__(256) void k_sort_col(const uint4* __restrict__ tmp,
                                                  const int* __restrict__ colBase,
                                                  uint4* __restrict__ csr,
                                                  int* __restrict__ offs) {
    __shared__ int h[256], sc[256], cur[256];
    int tid = threadIdx.x;
    int b = blockIdx.x;
    h[tid] = 0;
    __syncthreads();
    int base = colBase[b], cnt = colBase[b + 1] - base;
    for (int i = tid; i < cnt; i += 256) atomicAdd(&h[tmp[base + i].z & 255], 1);
    __syncthreads();
    int v = h[tid];
    sc[tid] = v;
    __syncthreads();
    for (int d = 1; d < 256; d <<= 1) {
        int a = (tid >= d) ? sc[tid - d] : 0;
        __syncthreads();
        sc[tid] += a;
        __syncthreads();
    }
    int excl = sc[tid] - v;
    int node = b * 256 + tid;
    if (node < NN) offs[node] = base + excl;
    if (b == NBUCK - 1 && tid == 0) offs[NN] = NE;
    cur[tid] = excl;
    __syncthreads();
    for (int i = tid; i < cnt; i += 256) {
        uint4 rec = tmp[base + i];
        int f = rec.z & 255;
        int pos = atomicAdd(&cur[f], 1);
        csr[base + pos] = rec;
    }
}

// ---------------- fp32 -> bf16 convert (input x, once) ----------------

__global__ __launch_bounds__(256) void k_x2bf(const float* __restrict__ x,
                                              ushort* __restrict__ xb) {
    int i = blockIdx.x * 256 + threadIdx.x;     // one float4 per thread
    float4 v = *(const float4*)&x[(size_t)i * 4];
    ushort4 o = {f2bf(v.x), f2bf(v.y), f2bf(v.z), f2bf(v.w)};
    *(ushort4*)&xb[(size_t)i * 4] = o;
}

// ---------------- BN folding helpers ----------------

__global__ void k_initAB(float* __restrict__ A, float* __restrict__ B) {
    int j = threadIdx.x;
    A[j] = 1.0f;
    B[j] = 0.0f;
}

// Wt[n][k] = bf16( A[k] * W[k][n] )  (transposed for MFMA B-fragment loads)
__global__ __launch_bounds__(128) void k_prep_wT(const float* __restrict__ W,
                                                 const float* __restrict__ A,
                                                 ushort* __restrict__ Wt) {
    int n = blockIdx.x, k = threadIdx.x;
    Wt[n * DIM + k] = f2bf(A[k] * W[k * DIM + n]);
}

// b_eff[j] = b[j] + sum_k B[k]*W[k][j]; also zero the BN stats accumulators
__global__ __launch_bounds__(128) void k_prep_b(const float* __restrict__ W,
                                                const float* __restrict__ b,
                                                const float* __restrict__ Bv,
                                                float* __restrict__ beff,
                                                float* __restrict__ stats) {
    int j = blockIdx.x, k = threadIdx.x;
    __shared__ float s[128];
    s[k] = Bv[k] * W[k * DIM + j];
    __syncthreads();
    for (int d = 64; d > 0; d >>= 1) {
        if (k < d) s[k] += s[k + d];
        __syncthreads();
    }
    if (k == 0) {
        beff[j] = b[j] + s[0];
        stats[j] = 0.0f;
        stats[DIM + j] = 0.0f;
    }
}

// ---------------- MFMA GEMM: Y[M,128] = A_bf[M,128] @ W + beff ----------------
// block = 256 (4 waves), wave computes 16 rows x 128 cols via 8 col-tiles.
// C/D: col = lane&15, row = quad*4 + reg  [measured: learn_hip m89/m91]

#define GEMM_MFMA_BODY(Abf, Wt)                                                     \
    const int lane = threadIdx.x & 63;                                              \
    const int wv   = threadIdx.x >> 6;                                              \
    const int m    = lane & 15;                                                     \
    const int quad = lane >> 4;                                                     \
    const int row0 = blockIdx.x * 64 + wv * 16;                                     \
    const int rr   = min(row0 + m, NN - 1);                                         \
    const short8* ap = (const short8*)&Abf[(size_t)rr * DIM + quad * 8];            \
    short8 a0 = ap[0];                                                              \
    short8 a1 = ap[4];                                                              \
    short8 a2 = ap[8];                                                              \
    short8 a3 = ap[12];                                                             \
    f32x4 acc[8];                                                                   \
    _Pragma("unroll")                                                               \
    for (int nt = 0; nt < 8; ++nt) {                                                \
        const short8* bp = (const short8*)&Wt[(size_t)(nt * 16 + m) * DIM + quad * 8]; \
        f32x4 c = {0.f, 0.f, 0.f, 0.f};                                             \
        c = __builtin_amdgcn_mfma_f32_16x16x32_bf16(a0, bp[0],  c, 0, 0, 0);        \
        c = __builtin_amdgcn_mfma_f32_16x16x32_bf16(a1, bp[4],  c, 0, 0, 0);        \
        c = __builtin_amdgcn_mfma_f32_16x16x32_bf16(a2, bp[8],  c, 0, 0, 0);        \
        c = __builtin_amdgcn_mfma_f32_16x16x32_bf16(a3, bp[12], c, 0, 0, 0);        \
        acc[nt] = c;                                                                \
    }                                                                               \
    const int rbase = row0 + quad * 4;

__global__ __launch_bounds__(256) void k_gemm_mf_bf(const ushort* __restrict__ Abf,
                                                    const ushort* __restrict__ Wt,
                                                    const float* __restrict__ beff,
                                                    ushort* __restrict__ Y) {
    GEMM_MFMA_BODY(Abf, Wt)
#pragma unroll
    for (int nt = 0; nt < 8; ++nt) {
        int col = nt * 16 + m;
        float bb = beff[col];
#pragma unroll
        for (int i = 0; i < 4; ++i) {
            int row = rbase + i;
            if (row < NN) Y[(size_t)row * DIM + col] = f2bf(acc[nt][i] + bb);
        }
    }
}

__global__ __launch_bounds__(256) void k_gemm_mf_f32(const ushort* __restrict__ Abf,
                                                     const ushort* __restrict__ Wt,
                                                     const float* __restrict__ beff,
                                                     float* __restrict__ Y) {
    GEMM_MFMA_BODY(Abf, Wt)
#pragma unroll
    for (int nt = 0; nt < 8; ++nt) {
        int col = nt * 16 + m;
        float bb = beff[col];
#pragma unroll
        for (int i = 0; i < 4; ++i) {
            int row = rbase + i;
            if (row < NN) Y[(size_t)row * DIM + col] = acc[nt][i] + bb;
        }
    }
}

// ---------------- aggregation + fused BN statistics ----------------
// wave processes 16 consecutive nodes; 4 edges per load instruction
// (lane = q*16 + oc); CSR padded with 8 zero-norm records for the tail.

__global__ __launch_bounds__(256) void k_agg(const float4* __restrict__ h4,
                                             const float4* __restrict__ csr,
                                             const int* __restrict__ offs,
                                             const float* __restrict__ We,
                                             const float* __restrict__ be,
                                             uint* __restrict__ tb,      // bf16 pairs
                                             float* __restrict__ partial) {
    int wv = threadIdx.x >> 6;
    int lane = threadIdx.x & 63;
    int q  = lane >> 4;        // 0..3: edge slot in group
    int oc = lane & 15;        // 0..15: col-octet
    int j0 = oc * 8;

    float4 w0a = *(const float4*)&We[j0];
    float4 w0b = *(const float4*)&We[j0 + 4];
    float4 w1a = *(const float4*)&We[DIM + j0];
    float4 w1b = *(const float4*)&We[DIM + j0 + 4];
    float4 w2a = *(const float4*)&We[2 * DIM + j0];
    float4 w2b = *(const float4*)&We[2 * DIM + j0 + 4];
    float4 bea = *(const float4*)&be[j0];
    float4 beb = *(const float4*)&be[j0 + 4];

    float4 sm0 = {0, 0, 0, 0}, sm1 = {0, 0, 0, 0};   // col sums
    float4 sq0 = {0, 0, 0, 0}, sq1 = {0, 0, 0, 0};   // col sumsq

    for (int it = 0; it < 16; ++it) {
        int v = blockIdx.x * 64 + wv * 16 + it;
        if (v >= NN) break;

        float4 accA = {0, 0, 0, 0}, accB = {0, 0, 0, 0};
        int s0 = offs[v], e0 = offs[v + 1];

        for (int base = s0; base < e0; base += 8) {
            int i1 = base + q;
            int i2 = base + 4 + q;
            float4 r1 = csr[i1];
            float4 r2 = csr[i2];
            int row1 = __float_as_int(r1.w);
            int row2 = __float_as_int(r2.w);
            float4 hv1 = h4[(size_t)row1 * 16 + oc];
            float4 hv2 = h4[(size_t)row2 * 16 + oc];
            float n1 = (i1 < e0) ? r1.x : 0.0f;
            float n2 = (i2 < e0) ? r2.x : 0.0f;

            {
                uint py = __float_as_uint(r1.y), pz = __float_as_uint(r1.z);
                float a0 = bf_hi(py), a1 = bf_lo(py), a2 = bf_hi(pz);
                float4 eA, eB;
                eA.x = fmaf(a0, w0a.x, fmaf(a1, w1a.x, fmaf(a2, w2a.x, bea.x)));
                eA.y = fmaf(a0, w0a.y, fmaf(a1, w1a.y, fmaf(a2, w2a.y, bea.y)));
                eA.z = fmaf(a0, w0a.z, fmaf(a1, w1a.z, fmaf(a2, w2a.z, bea.z)));
                eA.w = fmaf(a0, w0a.w, fmaf(a1, w1a.w, fmaf(a2, w2a.w, bea.w)));
                eB.x = fmaf(a0, w0b.x, fmaf(a1, w1b.x, fmaf(a2, w2b.x, beb.x)));
                eB.y = fmaf(a0, w0b.y, fmaf(a1, w1b.y, fmaf(a2, w2b.y, beb.y)));
                eB.z = fmaf(a0, w0b.z, fmaf(a1, w1b.z, fmaf(a2, w2b.z, beb.z)));
                eB.w = fmaf(a0, w0b.w, fmaf(a1, w1b.w, fmaf(a2, w2b.w, beb.w)));
                uint hx = __float_as_uint(hv1.x), hy = __float_as_uint(hv1.y);
                uint hz = __float_as_uint(hv1.z), hw = __float_as_uint(hv1.w);
                accA.x = fmaf(n1, fmaxf(bf_lo(hx) + eA.x, 0.f), accA.x);
                accA.y = fmaf(n1, fmaxf(bf_hi(hx) + eA.y, 0.f), accA.y);
                accA.z = fmaf(n1, fmaxf(bf_lo(hy) + eA.z, 0.f), accA.z);
                accA.w = fmaf(n1, fmaxf(bf_hi(hy) + eA.w, 0.f), accA.w);
                accB.x = fmaf(n1, fmaxf(bf_lo(hz) + eB.x, 0.f), accB.x);
                accB.y = fmaf(n1, fmaxf(bf_hi(hz) + eB.y, 0.f), accB.y);
                accB.z = fmaf(n1, fmaxf(bf_lo(hw) + eB.z, 0.f), accB.z);
                accB.w = fmaf(n1, fmaxf(bf_hi(hw) + eB.w, 0.f), accB.w);
            }
            {
                uint py = __float_as_uint(r2.y), pz = __float_as_uint(r2.z);
                float a0 = bf_hi(py), a1 = bf_lo(py), a2 = bf_hi(pz);
                float4 eA, eB;
                eA.x = fmaf(a0, w0a.x, fmaf(a1, w1a.x, fmaf(a2, w2a.x, bea.x)));
                eA.y = fmaf(a0, w0a.y, fmaf(a1, w1a.y, fmaf(a2, w2a.y, bea.y)));
                eA.z = fmaf(a0, w0a.z, fmaf(a1, w1a.z, fmaf(a2, w2a.z, bea.z)));
                eA.w = fmaf(a0, w0a.w, fmaf(a1, w1a.w, fmaf(a2, w2a.w, bea.w)));
                eB.x = fmaf(a0, w0b.x, fmaf(a1, w1b.x, fmaf(a2, w2b.x, beb.x)));
                eB.y = fmaf(a0, w0b.y, fmaf(a1, w1b.y, fmaf(a2, w2b.y, beb.y)));
                eB.z = fmaf(a0, w0b.z, fmaf(a1, w1b.z, fmaf(a2, w2b.z, beb.z)));
                eB.w = fmaf(a0, w0b.w, fmaf(a1, w1b.w, fmaf(a2, w2b.w, beb.w)));
                uint hx = __float_as_uint(hv2.x), hy = __float_as_uint(hv2.y);
                uint hz = __float_as_uint(hv2.z), hw = __float_as_uint(hv2.w);
                accA.x = fmaf(n2, fmaxf(bf_lo(hx) + eA.x, 0.f), accA.x);
                accA.y = fmaf(n2, fmaxf(bf_hi(hx) + eA.y, 0.f), accA.y);
                accA.z = fmaf(n2, fmaxf(bf_lo(hy) + eA.z, 0.f), accA.z);
                accA.w = fmaf(n2, fmaxf(bf_hi(hy) + eA.w, 0.f), accA.w);
                accB.x = fmaf(n2, fmaxf(bf_lo(hz) + eB.x, 0.f), accB.x);
                accB.y = fmaf(n2, fmaxf(bf_hi(hz) + eB.y, 0.f), accB.y);
                accB.z = fmaf(n2, fmaxf(bf_lo(hw) + eB.z, 0.f), accB.z);
                accB.w = fmaf(n2, fmaxf(bf_hi(hw) + eB.w, 0.f), accB.w);
            }
        }

        // reduce across the 4 edge-quads (lanes with equal oc)
        accA.x += __shfl_xor(accA.x, 16); accA.x += __shfl_xor(accA.x, 32);
        accA.y += __shfl_xor(accA.y, 16); accA.y += __shfl_xor(accA.y, 32);
        accA.z += __shfl_xor(accA.z, 16); accA.z += __shfl_xor(accA.z, 32);
        accA.w += __shfl_xor(accA.w, 16); accA.w += __shfl_xor(accA.w, 32);
        accB.x += __shfl_xor(accB.x, 16); accB.x += __shfl_xor(accB.x, 32);
        accB.y += __shfl_xor(accB.y, 16); accB.y += __shfl_xor(accB.y, 32);
        accB.z += __shfl_xor(accB.z, 16); accB.z += __shfl_xor(accB.z, 32);
        accB.w += __shfl_xor(accB.w, 16); accB.w += __shfl_xor(accB.w, 32);

        if (q == 0) {
            float o0 = fmaxf(accA.x, 0.f), o1 = fmaxf(accA.y, 0.f);
            float o2 = fmaxf(accA.z, 0.f), o3 = fmaxf(accA.w, 0.f);
            float o4 = fmaxf(accB.x, 0.f), o5 = fmaxf(accB.y, 0.f);
            float o6 = fmaxf(accB.z, 0.f), o7 = fmaxf(accB.w, 0.f);
            sm0.x += o0; sm0.y += o1; sm0.z += o2; sm0.w += o3;
            sm1.x += o4; sm1.y += o5; sm1.z += o6; sm1.w += o7;
            sq0.x = fmaf(o0, o0, sq0.x); sq0.y = fmaf(o1, o1, sq0.y);
            sq0.z = fmaf(o2, o2, sq0.z); sq0.w = fmaf(o3, o3, sq0.w);
            sq1.x = fmaf(o4, o4, sq1.x); sq1.y = fmaf(o5, o5, sq1.y);
            sq1.z = fmaf(o6, o6, sq1.z); sq1.w = fmaf(o7, o7, sq1.w);
            uint4 pk;
            pk.x = ((uint)f2bf(o1) << 16) | f2bf(o0);
            pk.y = ((uint)f2bf(o3) << 16) | f2bf(o2);
            pk.z = ((uint)f2bf(o5) << 16) | f2bf(o4);
            pk.w = ((uint)f2bf(o7) << 16) | f2bf(o6);
            *(uint4*)&tb[(size_t)v * 64 + oc * 4] = pk;
        }
    }

    if (q == 0) {
        int w = blockIdx.x * 4 + wv;
        float* pp = &partial[(size_t)w * 256 + oc * 8];
        *(float4*)pp = sm0;
        *(float4*)(pp + 4) = sm1;
        *(float4*)(pp + 128) = sq0;
        *(float4*)(pp + 132) = sq1;
    }
}

// reduce per-wave partials into stats[256]
__global__ __launch_bounds__(256) void k_red(const float* __restrict__ partial,
                                             float* __restrict__ stats) {
    float s = 0.0f;
    for (int w = blockIdx.x; w < NWAVES_AGG; w += 64)
        s += partial[(size_t)w * 256 + threadIdx.x];
    atomicAdd(&stats[threadIdx.x], s);
}

__global__ void k_coeff(const float* __restrict__ stats,
                        const float* __restrict__ g,
                        const float* __restrict__ bt,
                        float* __restrict__ A, float* __restrict__ B) {
    int j = threadIdx.x;
    float m = stats[j] * (1.0f / NN);
    float var = stats[DIM + j] * (1.0f / NN) - m * m;
    float rs = rsqrtf(var + BN_EPS);
    float a = rs * g[j];
    A[j] = a;
    B[j] = bt[j] - m * a;
}

// ---------------- launch ----------------

static inline char* alignp(char* p, size_t a) {
    return (char*)(((uintptr_t)p + a - 1) & ~(uintptr_t)(a - 1));
}

extern "C" void kernel_launch(void* const* d_in, const int* in_sizes, int n_in,
                              void* d_out, int out_size, void* d_ws, size_t ws_size,
                              hipStream_t stream) {
    const float* x   = (const float*)d_in[0];
    const int*   ei  = (const int*)d_in[1];
    const float* ea  = (const float*)d_in[2];
    const float* Wp[3]  = {(const float*)d_in[3],  (const float*)d_in[9],  (const float*)d_in[15]};
    const float* bp[3]  = {(const float*)d_in[4],  (const float*)d_in[10], (const float*)d_in[16]};
    const float* Wep[3] = {(const float*)d_in[5],  (const float*)d_in[11], (const float*)d_in[17]};
    const float* bep[3] = {(const float*)d_in[6],  (const float*)d_in[12], (const float*)d_in[18]};
    const float* gp[3]  = {(const float*)d_in[7],  (const float*)d_in[13], (const float*)d_in[19]};
    const float* btp[3] = {(const float*)d_in[8],  (const float*)d_in[14], (const float*)d_in[20]};
    const float* Wl  = (const float*)d_in[21];
    const float* bl  = (const float*)d_in[22];
    float* out = (float*)d_out;

    char* p = (char*)d_ws;
    auto alloc = [&](size_t bytes) -> void* {
        p = alignp(p, 256);
        void* r = (void*)p;
        p += bytes;
        return r;
    };

    int*    bcnt     = (int*)alloc(2 * NBUCK * sizeof(int));       // rowCnt | colCnt
    int*    rowCnt   = bcnt;
    int*    colCnt   = bcnt + NBUCK;
    int*    rowBase  = (int*)alloc((NBUCK + 1) * sizeof(int));
    int*    colBase  = (int*)alloc((NBUCK + 1) * sizeof(int));
    int*    rowCur   = (int*)alloc(NBUCK * sizeof(int));
    int*    colCur   = (int*)alloc(NBUCK * sizeof(int));
    int*    offs     = (int*)alloc((NN + 1) * sizeof(int));
    float*  dinv     = (float*)alloc(NN * sizeof(float));
    uchar*  rowScat  = (uchar*)alloc(NE * sizeof(uchar));
    uint4*  csr      = (uint4*)alloc(((size_t)NE + 8) * sizeof(uint4));
    ushort* x_bf     = (ushort*)alloc((size_t)NN * DIM * sizeof(ushort));
    ushort* h_bf     = (ushort*)alloc((size_t)NN * DIM * sizeof(ushort));
    ushort* t_bf     = (ushort*)alloc((size_t)NN * DIM * sizeof(ushort));
    float*  partial  = (float*)alloc((size_t)NWAVES_AGG * 256 * sizeof(float));
    ushort* Wt       = (ushort*)alloc(DIM * DIM * sizeof(ushort));
    float*  beff     = (float*)alloc(DIM * sizeof(float));
    float*  Av       = (float*)alloc(DIM * sizeof(float));
    float*  Bv       = (float*)alloc(DIM * sizeof(float));
    float*  stats    = (float*)alloc(2 * DIM * sizeof(float));

    // tmp (bucket-scattered records) aliases t_bf: both 25.6 MB; tmp dies at
    // k_sort_col, t_bf is first written by layer-1 k_agg (strictly later).
    uint4* tmp = (uint4*)t_bf;

    // --- setup: bucket-sorted CSR (no million-scale device atomics) ---
    hipMemsetAsync(bcnt, 0, 2 * NBUCK * sizeof(int), stream);
    hipMemsetAsync(csr + NE, 0, 8 * sizeof(uint4), stream);       // zero-norm pad
    k_count<<<NB_CNT, 256, 0, stream>>>(ei, rowCnt, colCnt);
    k_scanb<<<1, 512, 0, stream>>>(rowCnt, colCnt, rowBase, colBase, rowCur, colCur);
    k_scat_row<<<NB_CNT, 256, 0, stream>>>(ei, rowCur, rowScat);
    k_deg<<<NBUCK, 256, 0, stream>>>(rowScat, rowBase, dinv);
    k_scat_col<<<NB_SCC, 256, 0, stream>>>(ei, ea, dinv, colCur, tmp);
    k_sort_col<<<NBUCK, 256, 0, stream>>>(tmp, colBase, csr, offs);

    k_x2bf<<<NN * DIM / 4 / 256, 256, 0, stream>>>(x, x_bf);
    k_initAB<<<1, 128, 0, stream>>>(Av, Bv);

    const ushort* Xbf = x_bf;
    for (int l = 0; l < 3; ++l) {
        k_prep_wT<<<128, 128, 0, stream>>>(Wp[l], Av, Wt);
        k_prep_b<<<128, 128, 0, stream>>>(Wp[l], bp[l], Bv, beff, stats);
        k_gemm_mf_bf<<<NBLK_GEMM, 256, 0, stream>>>(Xbf, Wt, beff, h_bf);
        k_agg<<<NBLK_AGG, 256, 0, stream>>>((const float4*)h_bf, (const float4*)csr, offs,
                                            Wep[l], bep[l], (uint*)t_bf, partial);
        k_red<<<64, 256, 0, stream>>>(partial, stats);
        k_coeff<<<1, 128, 0, stream>>>(stats, gp[l], btp[l], Av, Bv);
        Xbf = t_bf;
    }

    k_prep_wT<<<128, 128, 0, stream>>>(Wl, Av, Wt);
    k_prep_b<<<128, 128, 0, stream>>>(Wl, bl, Bv, beff, stats);
    k_gemm_mf_f32<<<NBLK_GEMM, 256, 0, stream>>>(t_bf, Wt, beff, out);
}

// Round 6
// 825.702 us; speedup vs baseline: 1.8580x; 1.0492x over previous
//
#include <hip/hip_runtime.h>
#include <stdint.h>

#define NN 100000
#define NE 1600000
#define DIM 128
#define BN_EPS 1e-5f
#define NBUCK 391               // ceil(NN/256) col/row buckets of 256 nodes
#define NBLK_GEMM 1563          // ceil(100000/64)
#define NBLK_AGG 6250           // 16 nodes/block: 4 waves x 4 nodes
#define NPART NBLK_AGG
#define NB_CNT 196              // ceil(NE/8192)
#define NB_SCC 391              // ceil(NE/4096)

typedef unsigned int uint;
typedef unsigned short ushort;
typedef unsigned char uchar;
typedef __attribute__((ext_vector_type(8))) short short8;   // 8 x bf16 (4 VGPRs)
typedef __attribute__((ext_vector_type(4))) float f32x4;
typedef __attribute__((ext_vector_type(2))) float v2f;      // packed fp32 pair

// ---------------- bf16 helpers ----------------

static __device__ __forceinline__ ushort f2bf(float f) {
    uint u = __float_as_uint(f);
    u += 0x7FFF + ((u >> 16) & 1);   // round-to-nearest-even
    return (ushort)(u >> 16);
}
static __device__ __forceinline__ float bf_lo(uint p) { return __uint_as_float(p << 16); }
static __device__ __forceinline__ float bf_hi(uint p) { return __uint_as_float(p & 0xFFFF0000u); }

static __device__ __forceinline__ v2f vfma(v2f a, v2f b, v2f c) {
    return __builtin_elementwise_fma(a, b, c);   // -> v_pk_fma_f32
}
static __device__ __forceinline__ v2f vbc(float s) { v2f r = {s, s}; return r; }

// ============ setup: bucket-sort CSR build (no million-scale atomics) ============

__global__ __launch_bounds__(256) void k_count(const int* __restrict__ ei,
                                               int* __restrict__ rowCnt,
                                               int* __restrict__ colCnt) {
    __shared__ int hr[NBUCK], hc[NBUCK];
    int tid = threadIdx.x;
    for (int b = tid; b < NBUCK; b += 256) { hr[b] = 0; hc[b] = 0; }
    __syncthreads();
    int e0 = blockIdx.x * 8192;
    int e1 = min(NE, e0 + 8192);
    for (int e = e0 + tid; e < e1; e += 256) {
        atomicAdd(&hr[ei[e] >> 8], 1);
        atomicAdd(&hc[ei[NE + e] >> 8], 1);
    }
    __syncthreads();
    for (int b = tid; b < NBUCK; b += 256) {
        if (hr[b]) atomicAdd(&rowCnt[b], hr[b]);
        if (hc[b]) atomicAdd(&colCnt[b], hc[b]);
    }
}

__global__ __launch_bounds__(512) void k_scanb(const int* __restrict__ rowCnt,
                                               const int* __restrict__ colCnt,
                                               int* __restrict__ rowBase,
                                               int* __restrict__ colBase,
                                               int* __restrict__ rowCur,
                                               int* __restrict__ colCur) {
    __shared__ int s[512];
    int tid = threadIdx.x;
    int v = (tid < NBUCK) ? rowCnt[tid] : 0;
    s[tid] = v;
    __syncthreads();
    for (int d = 1; d < 512; d <<= 1) {
        int a = (tid >= d) ? s[tid - d] : 0;
        __syncthreads();
        s[tid] += a;
        __syncthreads();
    }
    if (tid < NBUCK) { int e = s[tid] - v; rowBase[tid] = e; rowCur[tid] = e; }
    if (tid == NBUCK) rowBase[NBUCK] = s[NBUCK];
    __syncthreads();
    v = (tid < NBUCK) ? colCnt[tid] : 0;
    s[tid] = v;
    __syncthreads();
    for (int d = 1; d < 512; d <<= 1) {
        int a = (tid >= d) ? s[tid - d] : 0;
        __syncthreads();
        s[tid] += a;
        __syncthreads();
    }
    if (tid < NBUCK) { int e = s[tid] - v; colBase[tid] = e; colCur[tid] = e; }
    if (tid == NBUCK) colBase[NBUCK] = s[NBUCK];
}

__global__ __launch_bounds__(256) void k_scat_row(const int* __restrict__ ei,
                                                  int* __restrict__ rowCur,
                                                  uchar* __restrict__ rowScat) {
    __shared__ int h[NBUCK], lb[NBUCK], lc[NBUCK];
    int tid = threadIdx.x;
    for (int b = tid; b < NBUCK; b += 256) { h[b] = 0; lc[b] = 0; }
    __syncthreads();
    int e0 = blockIdx.x * 8192;
    int e1 = min(NE, e0 + 8192);
    for (int e = e0 + tid; e < e1; e += 256) atomicAdd(&h[ei[e] >> 8], 1);
    __syncthreads();
    for (int b = tid; b < NBUCK; b += 256)
        lb[b] = h[b] ? atomicAdd(&rowCur[b], h[b]) : 0;
    __syncthreads();
    for (int e = e0 + tid; e < e1; e += 256) {
        int r = ei[e];
        int b = r >> 8;
        int pos = lb[b] + atomicAdd(&lc[b], 1);
        rowScat[pos] = (uchar)(r & 255);
    }
}

__global__ __launch_bounds__(256) void k_deg(const uchar* __restrict__ rowScat,
                                             const int* __restrict__ rowBase,
                                             float* __restrict__ dinv) {
    __shared__ int h[256];
    int tid = threadIdx.x;
    int b = blockIdx.x;
    h[tid] = 0;
    __syncthreads();
    int base = rowBase[b], cnt = rowBase[b + 1] - base;
    for (int i = tid; i < cnt; i += 256) atomicAdd(&h[rowScat[base + i]], 1);
    __syncthreads();
    int node = b * 256 + tid;
    if (node < NN) dinv[node] = rsqrtf((float)h[tid] + 1.0f);
}

// record: {norm, bf16(ea0)|bf16(ea1), bf16(ea2)|fine8, row}
__global__ __launch_bounds__(256) void k_scat_col(const int* __restrict__ ei,
                                                  const float* __restrict__ ea,
                                                  const float* __restrict__ dinv,
                                                  int* __restrict__ colCur,
                                                  uint4* __restrict__ tmp) {
    __shared__ int h[NBUCK], lb[NBUCK], lc[NBUCK];
    int tid = threadIdx.x;
    for (int b = tid; b < NBUCK; b += 256) { h[b] = 0; lc[b] = 0; }
    __syncthreads();
    int e0 = blockIdx.x * 4096;
    int e1 = min(NE, e0 + 4096);
    for (int e = e0 + tid; e < e1; e += 256) atomicAdd(&h[ei[NE + e] >> 8], 1);
    __syncthreads();
    for (int b = tid; b < NBUCK; b += 256)
        lb[b] = h[b] ? atomicAdd(&colCur[b], h[b]) : 0;
    __syncthreads();
    for (int e = e0 + tid; e < e1; e += 256) {
        int r = ei[e];
        int c = ei[NE + e];
        int b = c >> 8;
        int pos = lb[b] + atomicAdd(&lc[b], 1);
        uint4 rec;
        rec.x = __float_as_uint(dinv[r] * dinv[c]);
        rec.y = ((uint)f2bf(ea[e * 3]) << 16) | (uint)f2bf(ea[e * 3 + 1]);
        rec.z = ((uint)f2bf(ea[e * 3 + 2]) << 16) | (uint)(c & 255);
        rec.w = (uint)r;
        tmp[pos] = rec;
    }
}

__global__ __launch_bounds__(256) void k_sort_col(const uint4* __restrict__ tmp,
                                                  const int* __restrict__ colBase,
                                                  uint4* __restrict__ csr,
                                                  int* __restrict__ offs) {
    __shared__ int h[256], sc[256], cur[256];
    int tid = threadIdx.x;
    int b = blockIdx.x;
    h[tid] = 0;
    __syncthreads();
    int base = colBase[b], cnt = colBase[b + 1] - base;
    for (int i = tid; i < cnt; i += 256) atomicAdd(&h[tmp[base + i].z & 255], 1);
    __syncthreads();
    int v = h[tid];
    sc[tid] = v;
    __syncthreads();
    for (int d = 1; d < 256; d <<= 1) {
        int a = (tid >= d) ? sc[tid - d] : 0;
        __syncthreads();
        sc[tid] += a;
        __syncthreads();
    }
    int excl = sc[tid] - v;
    int node = b * 256 + tid;
    if (node < NN) offs[node] = base + excl;
    if (b == NBUCK - 1 && tid == 0) offs[NN] = NE;
    cur[tid] = excl;
    __syncthreads();
    for (int i = tid; i < cnt; i += 256) {
        uint4 rec = tmp[base + i];
        int f = rec.z & 255;
        int pos = atomicAdd(&cur[f], 1);
        csr[base + pos] = rec;
    }
}

// ---------------- fp32 -> bf16 convert (input x, once) ----------------

__global__ __launch_bounds__(256) void k_x2bf(const float* __restrict__ x,
                                              ushort* __restrict__ xb) {
    int i = blockIdx.x * 256 + threadIdx.x;
    float4 v = *(const float4*)&x[(size_t)i * 4];
    ushort4 o = {f2bf(v.x), f2bf(v.y), f2bf(v.z), f2bf(v.w)};
    *(ushort4*)&xb[(size_t)i * 4] = o;
}

// ---------------- fused BN-fold + weight prep ----------------
// grid 256 x 128. Blocks 0..127: Wt row n (bf16, transposed, A-scaled).
// Blocks 128..255: beff col j + zero snext stats.
// mode==0: identity BN (first layer); else A/B from sprev stats.

__global__ __launch_bounds__(128) void k_prep(const float* __restrict__ W,
                                              const float* __restrict__ b,
                                              const float* __restrict__ g,
                                              const float* __restrict__ bt,
                                              const float* __restrict__ sprev,
                                              float* __restrict__ snext,
                                              int mode,
                                              ushort* __restrict__ Wt,
                                              float* __restrict__ beff) {
    __shared__ float s[DIM];
    int k = threadIdx.x;
    float A = 1.0f, B = 0.0f;
    if (mode) {
        float m = sprev[k] * (1.0f / NN);
        float var = sprev[DIM + k] * (1.0f / NN) - m * m;
        float rs = rsqrtf(var + BN_EPS);
        A = rs * g[k];
        B = bt[k] - m * A;
    }
    if (blockIdx.x < DIM) {
        int n = blockIdx.x;
        Wt[n * DIM + k] = f2bf(A * W[k * DIM + n]);
    } else {
        int j = blockIdx.x - DIM;
        s[k] = B * W[k * DIM + j];
        __syncthreads();
        for (int d = 64; d > 0; d >>= 1) {
            if (k < d) s[k] += s[k + d];
            __syncthreads();
        }
        if (k == 0) {
            beff[j] = b[j] + s[0];
            snext[j] = 0.0f;
            snext[DIM + j] = 0.0f;
        }
    }
}

// ---------------- MFMA GEMM: Y[M,128] = A_bf[M,128] @ W + beff ----------------
// C/D: col = lane&15, row = quad*4 + reg  [measured: learn_hip m89/m91]

#define GEMM_MFMA_BODY(Abf, Wt)                                                     \
    const int lane = threadIdx.x & 63;                                              \
    const int wv   = threadIdx.x >> 6;                                              \
    const int m    = lane & 15;                                                     \
    const int quad = lane >> 4;                                                     \
    const int row0 = blockIdx.x * 64 + wv * 16;                                     \
    const int rr   = min(row0 + m, NN - 1);                                         \
    const short8* ap = (const short8*)&Abf[(size_t)rr * DIM + quad * 8];            \
    short8 a0 = ap[0];                                                              \
    short8 a1 = ap[4];                                                              \
    short8 a2 = ap[8];                                                              \
    short8 a3 = ap[12];                                                             \
    f32x4 acc[8];                                                                   \
    _Pragma("unroll")                                                               \
    for (int nt = 0; nt < 8; ++nt) {                                                \
        const short8* bp = (const short8*)&Wt[(size_t)(nt * 16 + m) * DIM + quad * 8]; \
        f32x4 c = {0.f, 0.f, 0.f, 0.f};                                             \
        c = __builtin_amdgcn_mfma_f32_16x16x32_bf16(a0, bp[0],  c, 0, 0, 0);        \
        c = __builtin_amdgcn_mfma_f32_16x16x32_bf16(a1, bp[4],  c, 0, 0, 0);        \
        c = __builtin_amdgcn_mfma_f32_16x16x32_bf16(a2, bp[8],  c, 0, 0, 0);        \
        c = __builtin_amdgcn_mfma_f32_16x16x32_bf16(a3, bp[12], c, 0, 0, 0);        \
        acc[nt] = c;                                                                \
    }                                                                               \
    const int rbase = row0 + quad * 4;

__global__ __launch_bounds__(256) void k_gemm_mf_bf(const ushort* __restrict__ Abf,
                                                    const ushort* __restrict__ Wt,
                                                    const float* __restrict__ beff,
                                                    ushort* __restrict__ Y) {
    GEMM_MFMA_BODY(Abf, Wt)
#pragma unroll
    for (int nt = 0; nt < 8; ++nt) {
        int col = nt * 16 + m;
        float bb = beff[col];
#pragma unroll
        for (int i = 0; i < 4; ++i) {
            int row = rbase + i;
            if (row < NN) Y[(size_t)row * DIM + col] = f2bf(acc[nt][i] + bb);
        }
    }
}

__global__ __launch_bounds__(256) void k_gemm_mf_f32(const ushort* __restrict__ Abf,
                                                     const ushort* __restrict__ Wt,
                                                     const float* __restrict__ beff,
                                                     float* __restrict__ Y) {
    GEMM_MFMA_BODY(Abf, Wt)
#pragma unroll
    for (int nt = 0; nt < 8; ++nt) {
        int col = nt * 16 + m;
        float bb = beff[col];
#pragma unroll
        for (int i = 0; i < 4; ++i) {
            int row = rbase + i;
            if (row < NN) Y[(size_t)row * DIM + col] = acc[nt][i] + bb;
        }
    }
}

// ---------------- aggregation + fused BN statistics ----------------
// wave processes 4 nodes; 4 edges per load instruction (lane = q*16 + oc).
// packed-fp32 (v_pk_fma_f32) math on v2f pairs; BN partials merged per block
// in LDS -> one 256-float partial per block.

__global__ __launch_bounds__(256) void k_agg(const float4* __restrict__ h4,
                                             const float4* __restrict__ csr,
                                             const int* __restrict__ offs,
                                             const float* __restrict__ We,
                                             const float* __restrict__ be,
                                             uint* __restrict__ tb,
                                             float* __restrict__ partial) {
    __shared__ float pbuf[4][256];
    int wv = threadIdx.x >> 6;
    int lane = threadIdx.x & 63;
    int q  = lane >> 4;
    int oc = lane & 15;
    int j0 = oc * 8;

    float4 t0, t1;
    t0 = *(const float4*)&We[j0];             t1 = *(const float4*)&We[j0 + 4];
    v2f w0[4] = {{t0.x, t0.y}, {t0.z, t0.w}, {t1.x, t1.y}, {t1.z, t1.w}};
    t0 = *(const float4*)&We[DIM + j0];       t1 = *(const float4*)&We[DIM + j0 + 4];
    v2f w1[4] = {{t0.x, t0.y}, {t0.z, t0.w}, {t1.x, t1.y}, {t1.z, t1.w}};
    t0 = *(const float4*)&We[2 * DIM + j0];   t1 = *(const float4*)&We[2 * DIM + j0 + 4];
    v2f w2[4] = {{t0.x, t0.y}, {t0.z, t0.w}, {t1.x, t1.y}, {t1.z, t1.w}};
    t0 = *(const float4*)&be[j0];             t1 = *(const float4*)&be[j0 + 4];
    v2f vbe[4] = {{t0.x, t0.y}, {t0.z, t0.w}, {t1.x, t1.y}, {t1.z, t1.w}};

    v2f smv[4] = {{0,0},{0,0},{0,0},{0,0}};
    v2f sqv[4] = {{0,0},{0,0},{0,0},{0,0}};

    for (int it = 0; it < 4; ++it) {
        int v = blockIdx.x * 16 + wv * 4 + it;   // NBLK_AGG*16 == NN exactly

        v2f acc[4] = {{0,0},{0,0},{0,0},{0,0}};
        int s0 = offs[v], e0 = offs[v + 1];

        for (int base = s0; base < e0; base += 8) {
            int i1 = base + q;
            int i2 = base + 4 + q;
            float4 r1 = csr[i1];
            float4 r2 = csr[i2];
            int row1 = __float_as_int(r1.w);
            int row2 = __float_as_int(r2.w);
            float4 hv1 = h4[(size_t)row1 * 16 + oc];
            float4 hv2 = h4[(size_t)row2 * 16 + oc];
            float n1 = (i1 < e0) ? r1.x : 0.0f;
            float n2 = (i2 < e0) ? r2.x : 0.0f;

            {
                uint py = __float_as_uint(r1.y), pz = __float_as_uint(r1.z);
                v2f va0 = vbc(bf_hi(py)), va1 = vbc(bf_lo(py)), va2 = vbc(bf_hi(pz));
                v2f vn = vbc(n1);
                uint hx = __float_as_uint(hv1.x), hy = __float_as_uint(hv1.y);
                uint hz = __float_as_uint(hv1.z), hw = __float_as_uint(hv1.w);
                v2f hp[4] = {{bf_lo(hx), bf_hi(hx)}, {bf_lo(hy), bf_hi(hy)},
                             {bf_lo(hz), bf_hi(hz)}, {bf_lo(hw), bf_hi(hw)}};
#pragma unroll
                for (int j = 0; j < 4; ++j) {
                    v2f e = vfma(va2, w2[j], vbe[j]);
                    e = vfma(va1, w1[j], e);
                    e = vfma(va0, w0[j], e);
                    v2f u = hp[j] + e;
                    u.x = fmaxf(u.x, 0.0f);
                    u.y = fmaxf(u.y, 0.0f);
                    acc[j] = vfma(vn, u, acc[j]);
                }
            }
            {
                uint py = __float_as_uint(r2.y), pz = __float_as_uint(r2.z);
                v2f va0 = vbc(bf_hi(py)), va1 = vbc(bf_lo(py)), va2 = vbc(bf_hi(pz));
                v2f vn = vbc(n2);
                uint hx = __float_as_uint(hv2.x), hy = __float_as_uint(hv2.y);
                uint hz = __float_as_uint(hv2.z), hw = __float_as_uint(hv2.w);
                v2f hp[4] = {{bf_lo(hx), bf_hi(hx)}, {bf_lo(hy), bf_hi(hy)},
                             {bf_lo(hz), bf_hi(hz)}, {bf_lo(hw), bf_hi(hw)}};
#pragma unroll
                for (int j = 0; j < 4; ++j) {
                    v2f e = vfma(va2, w2[j], vbe[j]);
                    e = vfma(va1, w1[j], e);
                    e = vfma(va0, w0[j], e);
                    v2f u = hp[j] + e;
                    u.x = fmaxf(u.x, 0.0f);
                    u.y = fmaxf(u.y, 0.0f);
                    acc[j] = vfma(vn, u, acc[j]);
                }
            }
        }

        // reduce across the 4 edge-quads (lanes with equal oc)
#pragma unroll
        for (int j = 0; j < 4; ++j) {
            acc[j].x += __shfl_xor(acc[j].x, 16); acc[j].x += __shfl_xor(acc[j].x, 32);
            acc[j].y += __shfl_xor(acc[j].y, 16); acc[j].y += __shfl_xor(acc[j].y, 32);
        }

        if (q == 0) {
            uint4 pk;
            uint pw[4];
#pragma unroll
            for (int j = 0; j < 4; ++j) {
                acc[j].x = fmaxf(acc[j].x, 0.0f);   // outer relu
                acc[j].y = fmaxf(acc[j].y, 0.0f);
                smv[j] = smv[j] + acc[j];
                sqv[j] = vfma(acc[j], acc[j], sqv[j]);
                pw[j] = ((uint)f2bf(acc[j].y) << 16) | f2bf(acc[j].x);
            }
            pk.x = pw[0]; pk.y = pw[1]; pk.z = pw[2]; pk.w = pw[3];
            *(uint4*)&tb[(size_t)v * 64 + oc * 4] = pk;
        }
    }

    if (q == 0) {
#pragma unroll
        for (int j = 0; j < 4; ++j) {
            pbuf[wv][j0 + 2 * j]       = smv[j].x;
            pbuf[wv][j0 + 2 * j + 1]   = smv[j].y;
            pbuf[wv][128 + j0 + 2 * j]     = sqv[j].x;
            pbuf[wv][128 + j0 + 2 * j + 1] = sqv[j].y;
        }
    }
    __syncthreads();
    int tid = threadIdx.x;
    float s = pbuf[0][tid] + pbuf[1][tid] + pbuf[2][tid] + pbuf[3][tid];
    partial[(size_t)blockIdx.x * 256 + tid] = s;
}

// reduce per-block partials into stats[256]
__global__ __launch_bounds__(256) void k_red(const float* __restrict__ partial,
                                             float* __restrict__ stats) {
    float s = 0.0f;
    for (int w = blockIdx.x; w < NPART; w += 64)
        s += partial[(size_t)w * 256 + threadIdx.x];
    atomicAdd(&stats[threadIdx.x], s);
}

// ---------------- launch ----------------

static inline char* alignp(char* p, size_t a) {
    return (char*)(((uintptr_t)p + a - 1) & ~(uintptr_t)(a - 1));
}

extern "C" void kernel_launch(void* const* d_in, const int* in_sizes, int n_in,
                              void* d_out, int out_size, void* d_ws, size_t ws_size,
                              hipStream_t stream) {
    const float* x   = (const float*)d_in[0];
    const int*   ei  = (const int*)d_in[1];
    const float* ea  = (const float*)d_in[2];
    const float* Wp[3]  = {(const float*)d_in[3],  (const float*)d_in[9],  (const float*)d_in[15]};
    const float* bp[3]  = {(const float*)d_in[4],  (const float*)d_in[10], (const float*)d_in[16]};
    const float* Wep[3] = {(const float*)d_in[5],  (const float*)d_in[11], (const float*)d_in[17]};
    const float* bep[3] = {(const float*)d_in[6],  (const float*)d_in[12], (const float*)d_in[18]};
    const float* gp[3]  = {(const float*)d_in[7],  (const float*)d_in[13], (const float*)d_in[19]};
    const float* btp[3] = {(const float*)d_in[8],  (const float*)d_in[14], (const float*)d_in[20]};
    const float* Wl  = (const float*)d_in[21];
    const float* bl  = (const float*)d_in[22];
    float* out = (float*)d_out;

    char* p = (char*)d_ws;
    auto alloc = [&](size_t bytes) -> void* {
        p = alignp(p, 256);
        void* r = (void*)p;
        p += bytes;
        return r;
    };

    int*    bcnt     = (int*)alloc(2 * NBUCK * sizeof(int));
    int*    rowCnt   = bcnt;
    int*    colCnt   = bcnt + NBUCK;
    int*    rowBase  = (int*)alloc((NBUCK + 1) * sizeof(int));
    int*    colBase  = (int*)alloc((NBUCK + 1) * sizeof(int));
    int*    rowCur   = (int*)alloc(NBUCK * sizeof(int));
    int*    colCur   = (int*)alloc(NBUCK * sizeof(int));
    int*    offs     = (int*)alloc((NN + 1) * sizeof(int));
    float*  dinv     = (float*)alloc(NN * sizeof(float));
    uchar*  rowScat  = (uchar*)alloc(NE * sizeof(uchar));
    uint4*  csr      = (uint4*)alloc(((size_t)NE + 8) * sizeof(uint4));
    ushort* x_bf     = (ushort*)alloc((size_t)NN * DIM * sizeof(ushort));
    ushort* h_bf     = (ushort*)alloc((size_t)NN * DIM * sizeof(ushort));
    ushort* t_bf     = (ushort*)alloc((size_t)NN * DIM * sizeof(ushort));
    float*  partial  = (float*)alloc((size_t)NPART * 256 * sizeof(float));
    ushort* Wt       = (ushort*)alloc(DIM * DIM * sizeof(ushort));
    float*  beff     = (float*)alloc(DIM * sizeof(float));
    float*  sb0      = (float*)alloc(2 * DIM * sizeof(float));
    float*  sb1      = (float*)alloc(2 * DIM * sizeof(float));

    // tmp (bucket-scattered records) aliases t_bf: both 25.6 MB; tmp dies at
    // k_sort_col, t_bf is first written by layer-1 k_agg (strictly later).
    uint4* tmp = (uint4*)t_bf;

    hipMemsetAsync(bcnt, 0, 2 * NBUCK * sizeof(int), stream);
    hipMemsetAsync(csr + NE, 0, 8 * sizeof(uint4), stream);       // zero-norm pad
    k_count<<<NB_CNT, 256, 0, stream>>>(ei, rowCnt, colCnt);
    k_scanb<<<1, 512, 0, stream>>>(rowCnt, colCnt, rowBase, colBase, rowCur, colCur);
    k_scat_row<<<NB_CNT, 256, 0, stream>>>(ei, rowCur, rowScat);
    k_deg<<<NBUCK, 256, 0, stream>>>(rowScat, rowBase, dinv);
    k_scat_col<<<NB_SCC, 256, 0, stream>>>(ei, ea, dinv, colCur, tmp);
    k_sort_col<<<NBUCK, 256, 0, stream>>>(tmp, colBase, csr, offs);

    k_x2bf<<<NN * DIM / 4 / 256, 256, 0, stream>>>(x, x_bf);

    // stats double-buffer: scur(l) = (l&1)? sb1 : sb0; sprev(l) = the other.
    float* sbs[2] = {sb0, sb1};
    const ushort* Xbf = x_bf;
    for (int l = 0; l < 3; ++l) {
        float* scur = sbs[l & 1];
        float* sprev = sbs[(l + 1) & 1];
        const float* gg = (l == 0) ? gp[0] : gp[l - 1];
        const float* bb = (l == 0) ? btp[0] : btp[l - 1];
        k_prep<<<256, 128, 0, stream>>>(Wp[l], bp[l], gg, bb, sprev, scur,
                                        (l == 0) ? 0 : 1, Wt, beff);
        k_gemm_mf_bf<<<NBLK_GEMM, 256, 0, stream>>>(Xbf, Wt, beff, h_bf);
        k_agg<<<NBLK_AGG, 256, 0, stream>>>((const float4*)h_bf, (const float4*)csr, offs,
                                            Wep[l], bep[l], (uint*)t_bf, partial);
        k_red<<<64, 256, 0, stream>>>(partial, scur);
        Xbf = t_bf;
    }

    // final linear: BN3 folded (stats in scur(2) = sb0)
    k_prep<<<256, 128, 0, stream>>>(Wl, bl, gp[2], btp[2], sb0, sb1, 1, Wt, beff);
    k_gemm_mf_f32<<<NBLK_GEMM, 256, 0, stream>>>(t_bf, Wt, beff, out);
}